// Round 1
// baseline (1938.150 us; speedup 1.0000x reference)
//
#include <hip/hip_runtime.h>
#include <hip/hip_bf16.h>
#include <cstdint>
#include <cstddef>

// ---------------------------------------------------------------------------
// ROGPL_79517024518975: 2-layer GCN + mean-aggr + prototype-routed MoE head.
// Strategy (round 0, correctness-first, fp32 throughout):
//   - CSR build per call (hist -> scan -> scatter), no fp atomics anywhere.
//   - layer1: xagg = norm-agg(x)  (512-d), h1 = relu(xagg@W1 + b1)
//   - layer2: t = h1@W2 (256-d), h2 = norm-agg(t) + b2  -> xc[:,0:256]
//   - neighbor = mean-agg(h2)                            -> xc[:,256:512]
//   - head: per-node wave: scores=xc@Wp^T, argmax, out = xc@We[idx]^T
// ---------------------------------------------------------------------------

__global__ void hist_kernel(const int* __restrict__ dst, int* __restrict__ counts, int e) {
    int i = blockIdx.x * blockDim.x + threadIdx.x;
    if (i < e) atomicAdd(&counts[dst[i]], 1);
}

__global__ __launch_bounds__(1024) void scan_kernel(const int* __restrict__ counts,
                                                    int* __restrict__ offsets,
                                                    int* __restrict__ cursor,
                                                    float* __restrict__ dinv,
                                                    int n, int e) {
    __shared__ int sdata[1024];
    const int t = threadIdx.x;
    const int chunk = (n + 1023) / 1024;
    const int beg = t * chunk;
    const int end = min(beg + chunk, n);
    int s = 0;
    for (int j = beg; j < end; ++j) s += counts[j];
    sdata[t] = s;
    __syncthreads();
    // Hillis-Steele inclusive scan over 1024 partials
    for (int off = 1; off < 1024; off <<= 1) {
        int v = (t >= off) ? sdata[t - off] : 0;
        __syncthreads();
        sdata[t] += v;
        __syncthreads();
    }
    int run = sdata[t] - s;  // exclusive base for this thread's chunk
    for (int j = beg; j < end; ++j) {
        int c = counts[j];
        offsets[j] = run;
        cursor[j]  = run;
        dinv[j] = rsqrtf((float)c + 1.0f);  // deg includes self-loop
        run += c;
    }
    if (t == 0) offsets[n] = e;
}

__global__ void scatter_kernel(const int* __restrict__ src, const int* __restrict__ dst,
                               int* __restrict__ cursor, int* __restrict__ ssrc, int e) {
    int i = blockIdx.x * blockDim.x + threadIdx.x;
    if (i < e) {
        int d = dst[i];
        int pos = atomicAdd(&cursor[d], 1);
        ssrc[pos] = src[i];
    }
}

// 512-d GCN-normalized aggregation of x (plus self-loop term). out[n,512] = ws A.
__global__ __launch_bounds__(256) void agg512_kernel(const float* __restrict__ x,
                                                     const int* __restrict__ ssrc,
                                                     const int* __restrict__ offsets,
                                                     const float* __restrict__ dinv,
                                                     float* __restrict__ out) {
    const int node = blockIdx.x;
    const int t = threadIdx.x;
    __shared__ int   s_src[256];
    __shared__ float s_w[256];
    const int beg = offsets[node], end = offsets[node + 1];
    const float di = dinv[node];
    float2 acc = make_float2(0.f, 0.f);
    for (int base = beg; base < end; base += 256) {
        int m = min(256, end - base);
        __syncthreads();
        if (t < m) {
            int s = ssrc[base + t];
            s_src[t] = s;
            s_w[t] = di * dinv[s];
        }
        __syncthreads();
        for (int k = 0; k < m; ++k) {
            int s = s_src[k];
            float w = s_w[k];
            float2 v = *(const float2*)&x[(size_t)s * 512 + 2 * t];
            acc.x = fmaf(w, v.x, acc.x);
            acc.y = fmaf(w, v.y, acc.y);
        }
    }
    {   // self-loop: dinv_i^2 * x_i
        float w = di * di;
        float2 v = *(const float2*)&x[(size_t)node * 512 + 2 * t];
        acc.x = fmaf(w, v.x, acc.x);
        acc.y = fmaf(w, v.y, acc.y);
    }
    *(float2*)&out[(size_t)node * 512 + 2 * t] = acc;
}

// 256-d GCN-normalized aggregation of h (stride 256) + self-loop + bias,
// written into xc columns [0,256) (row stride 512).
__global__ __launch_bounds__(256) void agg256_kernel(const float* __restrict__ h,
                                                     const int* __restrict__ ssrc,
                                                     const int* __restrict__ offsets,
                                                     const float* __restrict__ dinv,
                                                     const float* __restrict__ bias,
                                                     float* __restrict__ xc) {
    const int node = blockIdx.x;
    const int t = threadIdx.x;
    __shared__ int   s_src[256];
    __shared__ float s_w[256];
    const int beg = offsets[node], end = offsets[node + 1];
    const float di = dinv[node];
    float acc = 0.f;
    for (int base = beg; base < end; base += 256) {
        int m = min(256, end - base);
        __syncthreads();
        if (t < m) {
            int s = ssrc[base + t];
            s_src[t] = s;
            s_w[t] = di * dinv[s];
        }
        __syncthreads();
        for (int k = 0; k < m; ++k)
            acc = fmaf(s_w[k], h[(size_t)s_src[k] * 256 + t], acc);
    }
    acc = fmaf(di * di, h[(size_t)node * 256 + t], acc);
    xc[(size_t)node * 512 + t] = acc + bias[t];
}

// mean aggregation of h2 (= xc cols [0,256), stride 512) into xc cols [256,512).
__global__ __launch_bounds__(256) void mean_kernel(const int* __restrict__ ssrc,
                                                   const int* __restrict__ offsets,
                                                   float* __restrict__ xc) {
    const int node = blockIdx.x;
    const int t = threadIdx.x;
    __shared__ int s_src[256];
    const int beg = offsets[node], end = offsets[node + 1];
    float acc = 0.f;
    for (int base = beg; base < end; base += 256) {
        int m = min(256, end - base);
        __syncthreads();
        if (t < m) s_src[t] = ssrc[base + t];
        __syncthreads();
        for (int k = 0; k < m; ++k)
            acc += xc[(size_t)s_src[k] * 512 + t];
    }
    float cnt = (float)(end - beg);
    acc /= fmaxf(cnt, 1.f);
    xc[(size_t)node * 512 + 256 + t] = acc;
}

// C[M,N] = A[M,K] @ W[K,N] (+bias)(+relu).  BM=BN=128, BK=16, 8x8/thread.
template <bool RELU, bool BIAS>
__global__ __launch_bounds__(256) void gemm_kernel(const float* __restrict__ A,
                                                   const float* __restrict__ W,
                                                   const float* __restrict__ bias,
                                                   float* __restrict__ C,
                                                   int M, int N, int K) {
    constexpr int BM = 128, BN = 128, BK = 16;
    __shared__ float As[BK][BM + 4];
    __shared__ float Bs[BK][BN + 4];
    const int tid = threadIdx.x;
    const int bm = blockIdx.y * BM;
    const int bn = blockIdx.x * BN;
    const int tx = tid & 15;
    const int ty = tid >> 4;
    float acc[8][8];
#pragma unroll
    for (int i = 0; i < 8; ++i)
#pragma unroll
        for (int j = 0; j < 8; ++j) acc[i][j] = 0.f;

    for (int k0 = 0; k0 < K; k0 += BK) {
#pragma unroll
        for (int r = 0; r < 2; ++r) {  // A tile 128x16, transposed into LDS
            int i = tid + r * 256;
            int row = i >> 2;
            int kc = (i & 3) << 2;
            float4 v = make_float4(0.f, 0.f, 0.f, 0.f);
            int grow = bm + row;
            if (grow < M) v = *(const float4*)&A[(size_t)grow * K + k0 + kc];
            As[kc + 0][row] = v.x;
            As[kc + 1][row] = v.y;
            As[kc + 2][row] = v.z;
            As[kc + 3][row] = v.w;
        }
#pragma unroll
        for (int r = 0; r < 2; ++r) {  // B tile 16x128, direct
            int i = tid + r * 256;
            int kr = i >> 5;
            int col = (i & 31) << 2;
            *(float4*)&Bs[kr][col] = *(const float4*)&W[(size_t)(k0 + kr) * N + bn + col];
        }
        __syncthreads();
#pragma unroll
        for (int kk = 0; kk < BK; ++kk) {
            float a[8], b[8];
            *(float4*)&a[0] = *(const float4*)&As[kk][ty * 8];
            *(float4*)&a[4] = *(const float4*)&As[kk][ty * 8 + 4];
            *(float4*)&b[0] = *(const float4*)&Bs[kk][tx * 8];
            *(float4*)&b[4] = *(const float4*)&Bs[kk][tx * 8 + 4];
#pragma unroll
            for (int i = 0; i < 8; ++i)
#pragma unroll
                for (int j = 0; j < 8; ++j)
                    acc[i][j] = fmaf(a[i], b[j], acc[i][j]);
        }
        __syncthreads();
    }
#pragma unroll
    for (int i = 0; i < 8; ++i) {
        int row = bm + ty * 8 + i;
        if (row >= M) continue;
#pragma unroll
        for (int j4 = 0; j4 < 2; ++j4) {
            int col = bn + tx * 8 + j4 * 4;
            float4 v = make_float4(acc[i][j4 * 4 + 0], acc[i][j4 * 4 + 1],
                                   acc[i][j4 * 4 + 2], acc[i][j4 * 4 + 3]);
            if constexpr (BIAS) {
                v.x += bias[col + 0];
                v.y += bias[col + 1];
                v.z += bias[col + 2];
                v.w += bias[col + 3];
            }
            if constexpr (RELU) {
                v.x = fmaxf(v.x, 0.f);
                v.y = fmaxf(v.y, 0.f);
                v.z = fmaxf(v.z, 0.f);
                v.w = fmaxf(v.w, 0.f);
            }
            *(float4*)&C[(size_t)row * N + col] = v;
        }
    }
}

// MoE head: one 64-lane wave per node.
__global__ __launch_bounds__(256) void expert_kernel(const float* __restrict__ xc,
                                                     const float* __restrict__ Wp,
                                                     const float* __restrict__ We,
                                                     float* __restrict__ out, int n) {
    const int wave = threadIdx.x >> 6;
    const int lane = threadIdx.x & 63;
    const int node = blockIdx.x * 4 + wave;
    if (node >= n) return;
    const float* row = xc + (size_t)node * 512;
    const float4 a = *(const float4*)&row[lane * 4];
    const float4 b = *(const float4*)&row[256 + lane * 4];

    float best = -3.0e38f;
    int bidx = 0;
#pragma unroll
    for (int c = 0; c < 8; ++c) {
        const float4 w0 = *(const float4*)&Wp[c * 512 + lane * 4];
        const float4 w1 = *(const float4*)&Wp[c * 512 + 256 + lane * 4];
        float p = a.x * w0.x + a.y * w0.y + a.z * w0.z + a.w * w0.w +
                  b.x * w1.x + b.y * w1.y + b.z * w1.z + b.w * w1.w;
#pragma unroll
        for (int off = 32; off; off >>= 1) p += __shfl_xor(p, off);
        if (p > best) { best = p; bidx = c; }  // first-max tiebreak, matches argmax
    }
    const float* we = We + (size_t)bidx * 40 * 512;
    for (int k = 0; k < 40; ++k) {
        const float4 w0 = *(const float4*)&we[k * 512 + lane * 4];
        const float4 w1 = *(const float4*)&we[k * 512 + 256 + lane * 4];
        float p = a.x * w0.x + a.y * w0.y + a.z * w0.z + a.w * w0.w +
                  b.x * w1.x + b.y * w1.y + b.z * w1.z + b.w * w1.w;
#pragma unroll
        for (int off = 32; off; off >>= 1) p += __shfl_xor(p, off);
        if (lane == 0) out[(size_t)node * 40 + k] = p;
    }
}

extern "C" void kernel_launch(void* const* d_in, const int* in_sizes, int n_in,
                              void* d_out, int out_size, void* d_ws, size_t ws_size,
                              hipStream_t stream) {
    const float* x  = (const float*)d_in[0];
    const int*  edge = (const int*)d_in[1];
    const float* W1 = (const float*)d_in[2];
    const float* b1 = (const float*)d_in[3];
    const float* W2 = (const float*)d_in[4];
    const float* b2 = (const float*)d_in[5];
    const float* Wp = (const float*)d_in[6];
    const float* We = (const float*)d_in[7];

    const int n = in_sizes[0] / 512;   // 50000
    const int e = in_sizes[1] / 2;     // 1600000
    const int* src = edge;
    const int* dst = edge + e;

    // workspace layout
    char* ws = (char*)d_ws;
    auto align16 = [](size_t v) { return (v + 15) & ~(size_t)15; };
    float* A = (float*)ws;                                   // [n,512] xagg / h2tmp
    float* B = (float*)(ws + (size_t)n * 512 * 4);           // [n,512] h1
    char* p = ws + (size_t)n * 512 * 4 * 2;
    float* dinv = (float*)p;    p += align16((size_t)n * 4);
    int* counts = (int*)p;      p += align16((size_t)n * 4);
    int* offsets = (int*)p;     p += align16((size_t)(n + 1) * 4);
    int* cursor = (int*)p;      p += align16((size_t)n * 4);
    int* ssrc = (int*)p;        // [e]

    float* out = (float*)d_out;                 // [n,40]
    float* xc = (float*)d_out + (size_t)n * 40; // [n,512]

    // CSR build
    hipMemsetAsync(counts, 0, (size_t)n * 4, stream);
    hist_kernel<<<(e + 255) / 256, 256, 0, stream>>>(dst, counts, e);
    scan_kernel<<<1, 1024, 0, stream>>>(counts, offsets, cursor, dinv, n, e);
    scatter_kernel<<<(e + 255) / 256, 256, 0, stream>>>(src, dst, cursor, ssrc, e);

    // layer 1: aggregate-then-transform (GCN is linear in x)
    agg512_kernel<<<n, 256, 0, stream>>>(x, ssrc, offsets, dinv, A);
    dim3 g1(512 / 128, (n + 127) / 128);
    gemm_kernel<true, true><<<g1, 256, 0, stream>>>(A, W1, b1, B, n, 512, 512);

    // layer 2: transform-then-aggregate (256-d aggregation is cheaper)
    dim3 g2(256 / 128, (n + 127) / 128);
    gemm_kernel<false, false><<<g2, 256, 0, stream>>>(B, W2, nullptr, A, n, 256, 512);
    agg256_kernel<<<n, 256, 0, stream>>>(A, ssrc, offsets, dinv, b2, xc);

    // neighbor mean of h2
    mean_kernel<<<n, 256, 0, stream>>>(ssrc, offsets, xc);

    // MoE head
    expert_kernel<<<(n + 3) / 4, 256, 0, stream>>>(xc, Wp, We, out, n);
}

// Round 2
// 1900.974 us; speedup vs baseline: 1.0196x; 1.0196x over previous
//
#include <hip/hip_runtime.h>
#include <hip/hip_bf16.h>
#include <cstdint>
#include <cstddef>

// ---------------------------------------------------------------------------
// ROGPL_79517024518975: 2-layer GCN + mean-aggr + prototype-routed MoE head.
// Round 1: wave-per-node gathers (no LDS/syncs, float4, shuffle-broadcast),
//          mean-aggregation fused into the expert head.
//   - CSR build per call (hist -> scan -> scatter), no fp atomics anywhere.
//   - layer1: xagg = norm-agg(x)  (512-d), h1 = relu(xagg@W1 + b1)
//   - layer2: t = h1@W2 (256-d), h2 = norm-agg(t) + b2  -> xc[:,0:256]
//   - head: mean-agg(h2) -> xc[:,256:512] (kept in regs), scores, argmax,
//           out = xc@We[idx]^T   (one wave per node)
// ---------------------------------------------------------------------------

__global__ void hist_kernel(const int* __restrict__ dst, int* __restrict__ counts, int e) {
    int i = blockIdx.x * blockDim.x + threadIdx.x;
    if (i < e) atomicAdd(&counts[dst[i]], 1);
}

__global__ __launch_bounds__(1024) void scan_kernel(const int* __restrict__ counts,
                                                    int* __restrict__ offsets,
                                                    int* __restrict__ cursor,
                                                    float* __restrict__ dinv,
                                                    int n, int e) {
    __shared__ int sdata[1024];
    const int t = threadIdx.x;
    const int chunk = (n + 1023) / 1024;
    const int beg = t * chunk;
    const int end = min(beg + chunk, n);
    int s = 0;
    for (int j = beg; j < end; ++j) s += counts[j];
    sdata[t] = s;
    __syncthreads();
    for (int off = 1; off < 1024; off <<= 1) {
        int v = (t >= off) ? sdata[t - off] : 0;
        __syncthreads();
        sdata[t] += v;
        __syncthreads();
    }
    int run = sdata[t] - s;
    for (int j = beg; j < end; ++j) {
        int c = counts[j];
        offsets[j] = run;
        cursor[j]  = run;
        dinv[j] = rsqrtf((float)c + 1.0f);  // deg includes self-loop
        run += c;
    }
    if (t == 0) offsets[n] = e;
}

__global__ void scatter_kernel(const int* __restrict__ src, const int* __restrict__ dst,
                               int* __restrict__ cursor, int* __restrict__ ssrc, int e) {
    int i = blockIdx.x * blockDim.x + threadIdx.x;
    if (i < e) {
        int d = dst[i];
        int pos = atomicAdd(&cursor[d], 1);
        ssrc[pos] = src[i];
    }
}

// ---- wave-per-node normalized aggregation, 512 cols -----------------------
// out[node] = sum_j dinv_i*dinv_j * x[j]  +  dinv_i^2 * x[node]
__global__ __launch_bounds__(256) void agg512_kernel(const float* __restrict__ x,
                                                     const int* __restrict__ ssrc,
                                                     const int* __restrict__ offsets,
                                                     const float* __restrict__ dinv,
                                                     float* __restrict__ out, int n) {
    const int lane = threadIdx.x & 63;
    const int node = (blockIdx.x * blockDim.x + threadIdx.x) >> 6;
    if (node >= n) return;
    const int beg = offsets[node], end = offsets[node + 1];
    const float di = dinv[node];
    const int c0 = lane * 4;
    float4 acc0 = make_float4(0.f, 0.f, 0.f, 0.f);
    float4 acc1 = make_float4(0.f, 0.f, 0.f, 0.f);
    for (int base = beg; base < end; base += 64) {
        const int idx = base + lane;
        const int sl = (idx < end) ? ssrc[idx] : 0;
        const float wl = (idx < end) ? di * dinv[sl] : 0.f;
        const int m = min(64, end - base);
#pragma unroll 4
        for (int k = 0; k < m; ++k) {
            const int s = __shfl(sl, k);
            const float w = __shfl(wl, k);
            const float* r = &x[(size_t)s * 512];
            const float4 v0 = *(const float4*)&r[c0];
            const float4 v1 = *(const float4*)&r[c0 + 256];
            acc0.x = fmaf(w, v0.x, acc0.x); acc0.y = fmaf(w, v0.y, acc0.y);
            acc0.z = fmaf(w, v0.z, acc0.z); acc0.w = fmaf(w, v0.w, acc0.w);
            acc1.x = fmaf(w, v1.x, acc1.x); acc1.y = fmaf(w, v1.y, acc1.y);
            acc1.z = fmaf(w, v1.z, acc1.z); acc1.w = fmaf(w, v1.w, acc1.w);
        }
    }
    {   // self-loop
        const float w = di * di;
        const float* r = &x[(size_t)node * 512];
        const float4 v0 = *(const float4*)&r[c0];
        const float4 v1 = *(const float4*)&r[c0 + 256];
        acc0.x = fmaf(w, v0.x, acc0.x); acc0.y = fmaf(w, v0.y, acc0.y);
        acc0.z = fmaf(w, v0.z, acc0.z); acc0.w = fmaf(w, v0.w, acc0.w);
        acc1.x = fmaf(w, v1.x, acc1.x); acc1.y = fmaf(w, v1.y, acc1.y);
        acc1.z = fmaf(w, v1.z, acc1.z); acc1.w = fmaf(w, v1.w, acc1.w);
    }
    float* o = &out[(size_t)node * 512];
    *(float4*)&o[c0] = acc0;
    *(float4*)&o[c0 + 256] = acc1;
}

// ---- wave-per-node normalized aggregation, 256 cols, +bias ----------------
// input h [n,256]; output -> xc cols [0,256) (row stride 512)
__global__ __launch_bounds__(256) void agg256_kernel(const float* __restrict__ h,
                                                     const int* __restrict__ ssrc,
                                                     const int* __restrict__ offsets,
                                                     const float* __restrict__ dinv,
                                                     const float* __restrict__ bias,
                                                     float* __restrict__ xc, int n) {
    const int lane = threadIdx.x & 63;
    const int node = (blockIdx.x * blockDim.x + threadIdx.x) >> 6;
    if (node >= n) return;
    const int beg = offsets[node], end = offsets[node + 1];
    const float di = dinv[node];
    const int c0 = lane * 4;
    float4 acc = make_float4(0.f, 0.f, 0.f, 0.f);
    for (int base = beg; base < end; base += 64) {
        const int idx = base + lane;
        const int sl = (idx < end) ? ssrc[idx] : 0;
        const float wl = (idx < end) ? di * dinv[sl] : 0.f;
        const int m = min(64, end - base);
#pragma unroll 4
        for (int k = 0; k < m; ++k) {
            const int s = __shfl(sl, k);
            const float w = __shfl(wl, k);
            const float4 v = *(const float4*)&h[(size_t)s * 256 + c0];
            acc.x = fmaf(w, v.x, acc.x); acc.y = fmaf(w, v.y, acc.y);
            acc.z = fmaf(w, v.z, acc.z); acc.w = fmaf(w, v.w, acc.w);
        }
    }
    {   // self-loop + bias
        const float w = di * di;
        const float4 v = *(const float4*)&h[(size_t)node * 256 + c0];
        const float4 bv = *(const float4*)&bias[c0];
        acc.x = fmaf(w, v.x, acc.x) + bv.x;
        acc.y = fmaf(w, v.y, acc.y) + bv.y;
        acc.z = fmaf(w, v.z, acc.z) + bv.z;
        acc.w = fmaf(w, v.w, acc.w) + bv.w;
    }
    *(float4*)&xc[(size_t)node * 512 + c0] = acc;
}

// C[M,N] = A[M,K] @ W[K,N] (+bias)(+relu).  BM=BN=128, BK=16, 8x8/thread.
template <bool RELU, bool BIAS>
__global__ __launch_bounds__(256) void gemm_kernel(const float* __restrict__ A,
                                                   const float* __restrict__ W,
                                                   const float* __restrict__ bias,
                                                   float* __restrict__ C,
                                                   int M, int N, int K) {
    constexpr int BM = 128, BN = 128, BK = 16;
    __shared__ float As[BK][BM + 4];
    __shared__ float Bs[BK][BN + 4];
    const int tid = threadIdx.x;
    const int bm = blockIdx.y * BM;
    const int bn = blockIdx.x * BN;
    const int tx = tid & 15;
    const int ty = tid >> 4;
    float acc[8][8];
#pragma unroll
    for (int i = 0; i < 8; ++i)
#pragma unroll
        for (int j = 0; j < 8; ++j) acc[i][j] = 0.f;

    for (int k0 = 0; k0 < K; k0 += BK) {
#pragma unroll
        for (int r = 0; r < 2; ++r) {
            int i = tid + r * 256;
            int row = i >> 2;
            int kc = (i & 3) << 2;
            float4 v = make_float4(0.f, 0.f, 0.f, 0.f);
            int grow = bm + row;
            if (grow < M) v = *(const float4*)&A[(size_t)grow * K + k0 + kc];
            As[kc + 0][row] = v.x;
            As[kc + 1][row] = v.y;
            As[kc + 2][row] = v.z;
            As[kc + 3][row] = v.w;
        }
#pragma unroll
        for (int r = 0; r < 2; ++r) {
            int i = tid + r * 256;
            int kr = i >> 5;
            int col = (i & 31) << 2;
            *(float4*)&Bs[kr][col] = *(const float4*)&W[(size_t)(k0 + kr) * N + bn + col];
        }
        __syncthreads();
#pragma unroll
        for (int kk = 0; kk < BK; ++kk) {
            float a[8], b[8];
            *(float4*)&a[0] = *(const float4*)&As[kk][ty * 8];
            *(float4*)&a[4] = *(const float4*)&As[kk][ty * 8 + 4];
            *(float4*)&b[0] = *(const float4*)&Bs[kk][tx * 8];
            *(float4*)&b[4] = *(const float4*)&Bs[kk][tx * 8 + 4];
#pragma unroll
            for (int i = 0; i < 8; ++i)
#pragma unroll
                for (int j = 0; j < 8; ++j)
                    acc[i][j] = fmaf(a[i], b[j], acc[i][j]);
        }
        __syncthreads();
    }
#pragma unroll
    for (int i = 0; i < 8; ++i) {
        int row = bm + ty * 8 + i;
        if (row >= M) continue;
#pragma unroll
        for (int j4 = 0; j4 < 2; ++j4) {
            int col = bn + tx * 8 + j4 * 4;
            float4 v = make_float4(acc[i][j4 * 4 + 0], acc[i][j4 * 4 + 1],
                                   acc[i][j4 * 4 + 2], acc[i][j4 * 4 + 3]);
            if constexpr (BIAS) {
                v.x += bias[col + 0];
                v.y += bias[col + 1];
                v.z += bias[col + 2];
                v.w += bias[col + 3];
            }
            if constexpr (RELU) {
                v.x = fmaxf(v.x, 0.f);
                v.y = fmaxf(v.y, 0.f);
                v.z = fmaxf(v.z, 0.f);
                v.w = fmaxf(v.w, 0.f);
            }
            *(float4*)&C[(size_t)row * N + col] = v;
        }
    }
}

// ---- fused mean-aggregation + MoE head: one wave per node -----------------
// mean over neighbors of h2 (= xc cols [0,256), stride 512) -> xc cols
// [256,512) and kept in regs; then scores = xc@Wp^T, argmax, out = xc@We[idx]^T.
__global__ __launch_bounds__(256) void mean_expert_kernel(const int* __restrict__ ssrc,
                                                          const int* __restrict__ offsets,
                                                          const float* __restrict__ Wp,
                                                          const float* __restrict__ We,
                                                          float* __restrict__ xc,
                                                          float* __restrict__ out, int n) {
    const int lane = threadIdx.x & 63;
    const int node = (blockIdx.x * blockDim.x + threadIdx.x) >> 6;
    if (node >= n) return;
    const int beg = offsets[node], end = offsets[node + 1];
    const int c0 = lane * 4;

    float4 b = make_float4(0.f, 0.f, 0.f, 0.f);  // neighbor mean of h2
    for (int base = beg; base < end; base += 64) {
        const int idx = base + lane;
        const int sl = (idx < end) ? ssrc[idx] : 0;
        const int m = min(64, end - base);
#pragma unroll 4
        for (int k = 0; k < m; ++k) {
            const int s = __shfl(sl, k);
            const float4 v = *(const float4*)&xc[(size_t)s * 512 + c0];
            b.x += v.x; b.y += v.y; b.z += v.z; b.w += v.w;
        }
    }
    const float inv = 1.f / fmaxf((float)(end - beg), 1.f);
    b.x *= inv; b.y *= inv; b.z *= inv; b.w *= inv;
    *(float4*)&xc[(size_t)node * 512 + 256 + c0] = b;

    const float4 a = *(const float4*)&xc[(size_t)node * 512 + c0];  // own h2

    float best = -3.0e38f;
    int bidx = 0;
#pragma unroll
    for (int c = 0; c < 8; ++c) {
        const float4 w0 = *(const float4*)&Wp[c * 512 + c0];
        const float4 w1 = *(const float4*)&Wp[c * 512 + 256 + c0];
        float p = a.x * w0.x + a.y * w0.y + a.z * w0.z + a.w * w0.w +
                  b.x * w1.x + b.y * w1.y + b.z * w1.z + b.w * w1.w;
#pragma unroll
        for (int off = 32; off; off >>= 1) p += __shfl_xor(p, off);
        if (p > best) { best = p; bidx = c; }  // first-max tiebreak
    }
    const float* we = We + (size_t)bidx * 40 * 512;
    for (int k = 0; k < 40; ++k) {
        const float4 w0 = *(const float4*)&we[k * 512 + c0];
        const float4 w1 = *(const float4*)&we[k * 512 + 256 + c0];
        float p = a.x * w0.x + a.y * w0.y + a.z * w0.z + a.w * w0.w +
                  b.x * w1.x + b.y * w1.y + b.z * w1.z + b.w * w1.w;
#pragma unroll
        for (int off = 32; off; off >>= 1) p += __shfl_xor(p, off);
        if (lane == 0) out[(size_t)node * 40 + k] = p;
    }
}

extern "C" void kernel_launch(void* const* d_in, const int* in_sizes, int n_in,
                              void* d_out, int out_size, void* d_ws, size_t ws_size,
                              hipStream_t stream) {
    const float* x  = (const float*)d_in[0];
    const int*  edge = (const int*)d_in[1];
    const float* W1 = (const float*)d_in[2];
    const float* b1 = (const float*)d_in[3];
    const float* W2 = (const float*)d_in[4];
    const float* b2 = (const float*)d_in[5];
    const float* Wp = (const float*)d_in[6];
    const float* We = (const float*)d_in[7];

    const int n = in_sizes[0] / 512;   // 50000
    const int e = in_sizes[1] / 2;     // 1600000
    const int* src = edge;
    const int* dst = edge + e;

    // workspace layout
    char* ws = (char*)d_ws;
    auto align16 = [](size_t v) { return (v + 15) & ~(size_t)15; };
    float* A = (float*)ws;                                   // [n,512] xagg / t
    float* B = (float*)(ws + (size_t)n * 512 * 4);           // [n,512] h1
    char* p = ws + (size_t)n * 512 * 4 * 2;
    float* dinv = (float*)p;    p += align16((size_t)n * 4);
    int* counts = (int*)p;      p += align16((size_t)n * 4);
    int* offsets = (int*)p;     p += align16((size_t)(n + 1) * 4);
    int* cursor = (int*)p;      p += align16((size_t)n * 4);
    int* ssrc = (int*)p;        // [e]

    float* out = (float*)d_out;                 // [n,40]
    float* xc = (float*)d_out + (size_t)n * 40; // [n,512]

    // CSR build
    hipMemsetAsync(counts, 0, (size_t)n * 4, stream);
    hist_kernel<<<(e + 255) / 256, 256, 0, stream>>>(dst, counts, e);
    scan_kernel<<<1, 1024, 0, stream>>>(counts, offsets, cursor, dinv, n, e);
    scatter_kernel<<<(e + 255) / 256, 256, 0, stream>>>(src, dst, cursor, ssrc, e);

    const int waves_grid = (n * 64 + 255) / 256;  // 4 nodes per 256-thread block

    // layer 1: aggregate-then-transform (GCN is linear in x)
    agg512_kernel<<<waves_grid, 256, 0, stream>>>(x, ssrc, offsets, dinv, A, n);
    dim3 g1(512 / 128, (n + 127) / 128);
    gemm_kernel<true, true><<<g1, 256, 0, stream>>>(A, W1, b1, B, n, 512, 512);

    // layer 2: transform-then-aggregate (256-d aggregation is cheaper)
    dim3 g2(256 / 128, (n + 127) / 128);
    gemm_kernel<false, false><<<g2, 256, 0, stream>>>(B, W2, nullptr, A, n, 256, 512);
    agg256_kernel<<<waves_grid, 256, 0, stream>>>(A, ssrc, offsets, dinv, b2, xc, n);

    // fused neighbor-mean + MoE head
    mean_expert_kernel<<<waves_grid, 256, 0, stream>>>(ssrc, offsets, Wp, We, xc, out, n);
}

// Round 3
// 1531.691 us; speedup vs baseline: 1.2654x; 1.2411x over previous
//
#include <hip/hip_runtime.h>
#include <hip/hip_bf16.h>
#include <hip/hip_fp16.h>
#include <cstdint>
#include <cstddef>

// ---------------------------------------------------------------------------
// ROGPL_79517024518975: 2-layer GCN + mean-aggr + prototype-routed MoE head.
// Round 3:
//  - GEMMs via split-bf16 MFMA (4-term: hi/lo x hi/lo, fp32 accumulate) ->
//    fp32-class accuracy at bf16 matrix-core rate.
//  - agg512 emits A as bf16 hi/lo pair directly; GEMM1 epilogue emits h1 pair.
//  - M processed in 2 halves of 25000 rows so buffers alias into <=163MB ws.
//  - Head: We in fp16 (post-argmax only; Wp stays fp32 for routing safety),
//    mean gather reads fp16 copy of h2.
//  - Gathers: unroll 8.
// ---------------------------------------------------------------------------

using short8 = __attribute__((ext_vector_type(8))) short;
using f32x4  = __attribute__((ext_vector_type(4))) float;

#define GLB_AS __attribute__((address_space(1)))
#define LDS_AS __attribute__((address_space(3)))

__device__ inline ushort f2bf_rne(float v) {
    uint32_t u = __builtin_bit_cast(uint32_t, v);
    uint32_t r = (u + 0x7FFFu + ((u >> 16) & 1u)) >> 16;
    return (ushort)r;
}
__device__ inline float bf2f(ushort b) {
    uint32_t u = ((uint32_t)b) << 16;
    return __builtin_bit_cast(float, u);
}
__device__ inline void split1(float v, ushort& hi, ushort& lo) {
    hi = f2bf_rne(v);
    lo = f2bf_rne(v - bf2f(hi));
}

// ---------------- CSR build ------------------------------------------------
__global__ void hist_kernel(const int* __restrict__ dst, int* __restrict__ counts, int e) {
    int i = blockIdx.x * blockDim.x + threadIdx.x;
    if (i < e) atomicAdd(&counts[dst[i]], 1);
}

__global__ __launch_bounds__(1024) void scan_kernel(const int* __restrict__ counts,
                                                    int* __restrict__ offsets,
                                                    int* __restrict__ cursor,
                                                    float* __restrict__ dinv,
                                                    int n, int e) {
    __shared__ int sdata[1024];
    const int t = threadIdx.x;
    const int chunk = (n + 1023) / 1024;
    const int beg = t * chunk;
    const int end = min(beg + chunk, n);
    int s = 0;
    for (int j = beg; j < end; ++j) s += counts[j];
    sdata[t] = s;
    __syncthreads();
    for (int off = 1; off < 1024; off <<= 1) {
        int v = (t >= off) ? sdata[t - off] : 0;
        __syncthreads();
        sdata[t] += v;
        __syncthreads();
    }
    int run = sdata[t] - s;
    for (int j = beg; j < end; ++j) {
        int c = counts[j];
        offsets[j] = run;
        cursor[j]  = run;
        dinv[j] = rsqrtf((float)c + 1.0f);  // deg includes self-loop
        run += c;
    }
    if (t == 0) offsets[n] = e;
}

__global__ void scatter_kernel(const int* __restrict__ src, const int* __restrict__ dst,
                               int* __restrict__ cursor, int* __restrict__ ssrc, int e) {
    int i = blockIdx.x * blockDim.x + threadIdx.x;
    if (i < e) {
        int d = dst[i];
        int pos = atomicAdd(&cursor[d], 1);
        ssrc[pos] = src[i];
    }
}

// ---------------- weight preparation --------------------------------------
// W [K][N] fp32 -> WhT/WlT [N][K] bf16 hi/lo (transposed for MFMA B-frags)
__global__ void wsplit_kernel(const float* __restrict__ W, ushort* __restrict__ WhT,
                              ushort* __restrict__ WlT, int K, int nshift, int nmask) {
    int gid = blockIdx.x * blockDim.x + threadIdx.x;
    if (gid >= (K << nshift)) return;
    int k = gid >> nshift;
    int nn = gid & nmask;
    ushort hi, lo;
    split1(W[gid], hi, lo);
    WhT[(size_t)nn * K + k] = hi;
    WlT[(size_t)nn * K + k] = lo;
}

__global__ void weconv_kernel(const float* __restrict__ We, __half* __restrict__ We_h, int total) {
    int gid = blockIdx.x * blockDim.x + threadIdx.x;
    if (gid < total) We_h[gid] = __float2half(We[gid]);
}

// ---------------- wave-per-node aggregations -------------------------------
// 512-col GCN-normalized aggregation of x; emits bf16 hi/lo pair (GEMM A operand).
__global__ __launch_bounds__(256) void agg512_kernel(const float* __restrict__ x,
                                                     const int* __restrict__ ssrc,
                                                     const int* __restrict__ offsets,
                                                     const float* __restrict__ dinv,
                                                     ushort* __restrict__ A1,
                                                     ushort* __restrict__ A2,
                                                     int base, int cnt) {
    const int lane = threadIdx.x & 63;
    const int local = (blockIdx.x * blockDim.x + threadIdx.x) >> 6;
    if (local >= cnt) return;
    const int node = base + local;
    const int beg = offsets[node], end = offsets[node + 1];
    const float di = dinv[node];
    const int c0 = lane * 4;
    float4 acc0 = make_float4(0.f, 0.f, 0.f, 0.f);
    float4 acc1 = make_float4(0.f, 0.f, 0.f, 0.f);
    for (int b0 = beg; b0 < end; b0 += 64) {
        const int idx = b0 + lane;
        const int sl = (idx < end) ? ssrc[idx] : 0;
        const float wl = (idx < end) ? di * dinv[sl] : 0.f;
        const int m = min(64, end - b0);
#pragma unroll 8
        for (int k = 0; k < m; ++k) {
            const int s = __shfl(sl, k);
            const float w = __shfl(wl, k);
            const float* r = &x[(size_t)s * 512];
            const float4 v0 = *(const float4*)&r[c0];
            const float4 v1 = *(const float4*)&r[c0 + 256];
            acc0.x = fmaf(w, v0.x, acc0.x); acc0.y = fmaf(w, v0.y, acc0.y);
            acc0.z = fmaf(w, v0.z, acc0.z); acc0.w = fmaf(w, v0.w, acc0.w);
            acc1.x = fmaf(w, v1.x, acc1.x); acc1.y = fmaf(w, v1.y, acc1.y);
            acc1.z = fmaf(w, v1.z, acc1.z); acc1.w = fmaf(w, v1.w, acc1.w);
        }
    }
    {   // self-loop
        const float w = di * di;
        const float* r = &x[(size_t)node * 512];
        const float4 v0 = *(const float4*)&r[c0];
        const float4 v1 = *(const float4*)&r[c0 + 256];
        acc0.x = fmaf(w, v0.x, acc0.x); acc0.y = fmaf(w, v0.y, acc0.y);
        acc0.z = fmaf(w, v0.z, acc0.z); acc0.w = fmaf(w, v0.w, acc0.w);
        acc1.x = fmaf(w, v1.x, acc1.x); acc1.y = fmaf(w, v1.y, acc1.y);
        acc1.z = fmaf(w, v1.z, acc1.z); acc1.w = fmaf(w, v1.w, acc1.w);
    }
    // split to bf16 hi/lo
    ushort4 h0, l0, h1v, l1v;
    split1(acc0.x, h0.x, l0.x); split1(acc0.y, h0.y, l0.y);
    split1(acc0.z, h0.z, l0.z); split1(acc0.w, h0.w, l0.w);
    split1(acc1.x, h1v.x, l1v.x); split1(acc1.y, h1v.y, l1v.y);
    split1(acc1.z, h1v.z, l1v.z); split1(acc1.w, h1v.w, l1v.w);
    const size_t r = (size_t)local * 512;
    *(ushort4*)&A1[r + c0] = h0;       *(ushort4*)&A1[r + 256 + c0] = h1v;
    *(ushort4*)&A2[r + c0] = l0;       *(ushort4*)&A2[r + 256 + c0] = l1v;
}

// 256-col GCN-normalized aggregation of t (fp32) + bias -> xc cols [0,256)
// (fp32) and h2h (fp16 copy for the mean gather).
__global__ __launch_bounds__(256) void agg256_kernel(const float* __restrict__ t,
                                                     const int* __restrict__ ssrc,
                                                     const int* __restrict__ offsets,
                                                     const float* __restrict__ dinv,
                                                     const float* __restrict__ bias,
                                                     float* __restrict__ xc,
                                                     __half* __restrict__ h2h, int n) {
    const int lane = threadIdx.x & 63;
    const int node = (blockIdx.x * blockDim.x + threadIdx.x) >> 6;
    if (node >= n) return;
    const int beg = offsets[node], end = offsets[node + 1];
    const float di = dinv[node];
    const int c0 = lane * 4;
    float4 acc = make_float4(0.f, 0.f, 0.f, 0.f);
    for (int b0 = beg; b0 < end; b0 += 64) {
        const int idx = b0 + lane;
        const int sl = (idx < end) ? ssrc[idx] : 0;
        const float wl = (idx < end) ? di * dinv[sl] : 0.f;
        const int m = min(64, end - b0);
#pragma unroll 8
        for (int k = 0; k < m; ++k) {
            const int s = __shfl(sl, k);
            const float w = __shfl(wl, k);
            const float4 v = *(const float4*)&t[(size_t)s * 256 + c0];
            acc.x = fmaf(w, v.x, acc.x); acc.y = fmaf(w, v.y, acc.y);
            acc.z = fmaf(w, v.z, acc.z); acc.w = fmaf(w, v.w, acc.w);
        }
    }
    {   // self-loop + bias
        const float w = di * di;
        const float4 v = *(const float4*)&t[(size_t)node * 256 + c0];
        const float4 bv = *(const float4*)&bias[c0];
        acc.x = fmaf(w, v.x, acc.x) + bv.x;
        acc.y = fmaf(w, v.y, acc.y) + bv.y;
        acc.z = fmaf(w, v.z, acc.z) + bv.z;
        acc.w = fmaf(w, v.w, acc.w) + bv.w;
    }
    *(float4*)&xc[(size_t)node * 512 + c0] = acc;
    __half2 q01 = __floats2half2_rn(acc.x, acc.y);
    __half2 q23 = __floats2half2_rn(acc.z, acc.w);
    float2 pk;
    *(__half2*)&pk.x = q01;
    *(__half2*)&pk.y = q23;
    *(float2*)&h2h[(size_t)node * 256 + c0] = pk;
}

// ---------------- split-bf16 MFMA GEMM -------------------------------------
// C = (Ah+Al) @ (Wh+Wl)^T^T : 4-term MFMA accumulation, fp32 output class.
// A [M][K] bf16 pair; WT [N][K] bf16 pair (pre-transposed).
// EPI==1: v = relu(v + bias[col]); split to Ch/Cl bf16 pair (row stride ldc).
// EPI==0: Cf fp32 (row stride ldc).
template <int EPI>
__global__ __launch_bounds__(256) void gemm_split_kernel(
    const ushort* __restrict__ Ah, const ushort* __restrict__ Al,
    const ushort* __restrict__ WhT, const ushort* __restrict__ WlT,
    const float* __restrict__ bias,
    ushort* __restrict__ Ch, ushort* __restrict__ Cl,
    float* __restrict__ Cf,
    int M, int N, int K, int ldc) {
    __shared__ ushort smem[4 * 4096];  // A1s | A2s | B1s | B2s, each 128x32 bf16
    const int tid = threadIdx.x;
    const int lane = tid & 63;
    const int w = tid >> 6;
    const int wr = w >> 1, wc = w & 1;
    const int bm = blockIdx.y * 128;
    const int bn = blockIdx.x * 128;

    f32x4 acc[4][4];
#pragma unroll
    for (int i = 0; i < 4; ++i)
#pragma unroll
        for (int j = 0; j < 4; ++j) acc[i][j] = f32x4{0.f, 0.f, 0.f, 0.f};

    // wave w stages tile w: 0->Ah, 1->Al, 2->WhT, 3->WlT
    const ushort* sbase = (w == 0) ? Ah : (w == 1) ? Al : (w == 2) ? WhT : WlT;
    const int rowbase = (w < 2) ? bm : bn;
    const int rowmax = (w < 2) ? (M - 1) : (N - 1);

    for (int k0 = 0; k0 < K; k0 += 32) {
        __syncthreads();  // protect smem from previous iteration's reads
#pragma unroll
        for (int i = 0; i < 8; ++i) {
            const int c = i * 64 + lane;
            int row = rowbase + (c >> 2);
            row = min(row, rowmax);  // clamp tail rows (reads only, stores guarded)
            const ushort* g = sbase + (size_t)row * K + k0 + (c & 3) * 8;
            __builtin_amdgcn_global_load_lds((const GLB_AS void*)g,
                                             (LDS_AS void*)(smem + w * 4096 + i * 512),
                                             16, 0, 0);
        }
        __syncthreads();  // vmcnt(0) drained before barrier by compiler

        const int koff = (lane >> 4) * 8;
        const int rsel = lane & 15;
        short8 a1[4], a2[4], b1[4], b2[4];
#pragma unroll
        for (int f = 0; f < 4; ++f) {
            const int ar = wr * 64 + f * 16 + rsel;
            a1[f] = *(const short8*)&smem[0 * 4096 + ar * 32 + koff];
            a2[f] = *(const short8*)&smem[1 * 4096 + ar * 32 + koff];
            const int bc = wc * 64 + f * 16 + rsel;
            b1[f] = *(const short8*)&smem[2 * 4096 + bc * 32 + koff];
            b2[f] = *(const short8*)&smem[3 * 4096 + bc * 32 + koff];
        }
#pragma unroll
        for (int i = 0; i < 4; ++i)
#pragma unroll
            for (int j = 0; j < 4; ++j) {
                acc[i][j] = __builtin_amdgcn_mfma_f32_16x16x32_bf16(a1[i], b1[j], acc[i][j], 0, 0, 0);
                acc[i][j] = __builtin_amdgcn_mfma_f32_16x16x32_bf16(a1[i], b2[j], acc[i][j], 0, 0, 0);
                acc[i][j] = __builtin_amdgcn_mfma_f32_16x16x32_bf16(a2[i], b1[j], acc[i][j], 0, 0, 0);
                acc[i][j] = __builtin_amdgcn_mfma_f32_16x16x32_bf16(a2[i], b2[j], acc[i][j], 0, 0, 0);
            }
    }

    // epilogue: C/D layout col=lane&15, row=(lane>>4)*4+j (verified gfx950 map)
    const int crow0 = wr * 64 + (lane >> 4) * 4;
    const int ccol0 = wc * 64 + (lane & 15);
#pragma unroll
    for (int f = 0; f < 4; ++f) {
#pragma unroll
        for (int g = 0; g < 4; ++g) {
            const int colg = bn + ccol0 + g * 16;
            float bv = 0.f;
            if constexpr (EPI == 1) bv = bias[colg];
#pragma unroll
            for (int j = 0; j < 4; ++j) {
                const int rowg = bm + crow0 + f * 16 + j;
                if (rowg >= M) continue;
                float v = acc[f][g][j];
                if constexpr (EPI == 1) {
                    v = fmaxf(v + bv, 0.f);
                    ushort hi, lo;
                    split1(v, hi, lo);
                    Ch[(size_t)rowg * ldc + colg] = hi;
                    Cl[(size_t)rowg * ldc + colg] = lo;
                } else {
                    Cf[(size_t)rowg * ldc + colg] = v;
                }
            }
        }
    }
}

// ---------------- fused mean-aggregation + MoE head ------------------------
__global__ __launch_bounds__(256) void mean_expert_kernel(const int* __restrict__ ssrc,
                                                          const int* __restrict__ offsets,
                                                          const float* __restrict__ Wp,
                                                          const __half* __restrict__ We_h,
                                                          const __half* __restrict__ h2h,
                                                          float* __restrict__ xc,
                                                          float* __restrict__ out, int n) {
    const int lane = threadIdx.x & 63;
    const int node = (blockIdx.x * blockDim.x + threadIdx.x) >> 6;
    if (node >= n) return;
    const int beg = offsets[node], end = offsets[node + 1];
    const int c0 = lane * 4;

    float4 b = make_float4(0.f, 0.f, 0.f, 0.f);  // neighbor mean of h2
    for (int b0 = beg; b0 < end; b0 += 64) {
        const int idx = b0 + lane;
        const int sl = (idx < end) ? ssrc[idx] : 0;
        const int m = min(64, end - b0);
#pragma unroll 8
        for (int k = 0; k < m; ++k) {
            const int s = __shfl(sl, k);
            const float2 raw = *(const float2*)&h2h[(size_t)s * 256 + c0];
            const __half2 u01 = *(const __half2*)&raw.x;
            const __half2 u23 = *(const __half2*)&raw.y;
            const float2 f01 = __half22float2(u01);
            const float2 f23 = __half22float2(u23);
            b.x += f01.x; b.y += f01.y; b.z += f23.x; b.w += f23.y;
        }
    }
    const float inv = 1.f / fmaxf((float)(end - beg), 1.f);
    b.x *= inv; b.y *= inv; b.z *= inv; b.w *= inv;
    *(float4*)&xc[(size_t)node * 512 + 256 + c0] = b;

    const float4 a = *(const float4*)&xc[(size_t)node * 512 + c0];  // own h2 (fp32)

    // routing scores in fp32 (argmax flip safety)
    float best = -3.0e38f;
    int bidx = 0;
#pragma unroll
    for (int c = 0; c < 8; ++c) {
        const float4 w0 = *(const float4*)&Wp[c * 512 + c0];
        const float4 w1 = *(const float4*)&Wp[c * 512 + 256 + c0];
        float p = a.x * w0.x + a.y * w0.y + a.z * w0.z + a.w * w0.w +
                  b.x * w1.x + b.y * w1.y + b.z * w1.z + b.w * w1.w;
#pragma unroll
        for (int off = 32; off; off >>= 1) p += __shfl_xor(p, off);
        if (p > best) { best = p; bidx = c; }  // first-max tiebreak
    }
    const __half* we = We_h + (size_t)bidx * 40 * 512;
    for (int k = 0; k < 40; ++k) {
        const float2 r0 = *(const float2*)&we[k * 512 + c0];
        const float2 r1 = *(const float2*)&we[k * 512 + 256 + c0];
        const float2 w0a = __half22float2(*(const __half2*)&r0.x);
        const float2 w0b = __half22float2(*(const __half2*)&r0.y);
        const float2 w1a = __half22float2(*(const __half2*)&r1.x);
        const float2 w1b = __half22float2(*(const __half2*)&r1.y);
        float p = a.x * w0a.x + a.y * w0a.y + a.z * w0b.x + a.w * w0b.y +
                  b.x * w1a.x + b.y * w1a.y + b.z * w1b.x + b.w * w1b.y;
#pragma unroll
        for (int off = 32; off; off >>= 1) p += __shfl_xor(p, off);
        if (lane == 0) out[(size_t)node * 40 + k] = p;
    }
}

extern "C" void kernel_launch(void* const* d_in, const int* in_sizes, int n_in,
                              void* d_out, int out_size, void* d_ws, size_t ws_size,
                              hipStream_t stream) {
    const float* x  = (const float*)d_in[0];
    const int*  edge = (const int*)d_in[1];
    const float* W1 = (const float*)d_in[2];
    const float* b1 = (const float*)d_in[3];
    const float* W2 = (const float*)d_in[4];
    const float* b2 = (const float*)d_in[5];
    const float* Wp = (const float*)d_in[6];
    const float* We = (const float*)d_in[7];

    const int n = in_sizes[0] / 512;   // 50000
    const int e = in_sizes[1] / 2;     // 1600000
    const int half = n / 2;            // 25000
    const int* src = edge;
    const int* dst = edge + e;

    // ---- workspace layout (peak ~163 MB; aliasing documented) ----
    char* ws = (char*)d_ws;
    ushort* A1h = (ushort*)ws;                             // [half,512] bf16 hi
    ushort* A2h = (ushort*)(ws + (size_t)half * 512 * 2);  // [half,512] bf16 lo
    float*  t   = (float*)ws;                              // [n,256] fp32 (aliases A1h/A2h, after GEMM1)
    char* p = ws + (size_t)n * 512 * 2;                    // = 51.2 MB
    ushort* B1 = (ushort*)p; p += (size_t)n * 512 * 2;     // [n,512] h1 hi
    __half* h2h = (__half*)B1;                             // [n,256] fp16 (aliases B1, after GEMM2)
    ushort* B2 = (ushort*)p; p += (size_t)n * 512 * 2;     // [n,512] h1 lo
    ushort* W1hT = (ushort*)p; p += 512 * 512 * 2;
    ushort* W1lT = (ushort*)p; p += 512 * 512 * 2;
    ushort* W2hT = (ushort*)p; p += 256 * 512 * 2;
    ushort* W2lT = (ushort*)p; p += 256 * 512 * 2;
    __half* We_h = (__half*)p; p += 8 * 40 * 512 * 2;
    auto align16 = [](size_t v) { return (v + 15) & ~(size_t)15; };
    float* dinv = (float*)p;    p += align16((size_t)n * 4);
    int* counts = (int*)p;      p += align16((size_t)n * 4);
    int* offsets = (int*)p;     p += align16((size_t)(n + 1) * 4);
    int* cursor = (int*)p;      p += align16((size_t)n * 4);
    int* ssrc = (int*)p;        // [e]

    float* out = (float*)d_out;                 // [n,40]
    float* xc = (float*)d_out + (size_t)n * 40; // [n,512]

    // ---- CSR build ----
    hipMemsetAsync(counts, 0, (size_t)n * 4, stream);
    hist_kernel<<<(e + 255) / 256, 256, 0, stream>>>(dst, counts, e);
    scan_kernel<<<1, 1024, 0, stream>>>(counts, offsets, cursor, dinv, n, e);
    scatter_kernel<<<(e + 255) / 256, 256, 0, stream>>>(src, dst, cursor, ssrc, e);

    // ---- weight prep ----
    wsplit_kernel<<<(512 * 512 + 255) / 256, 256, 0, stream>>>(W1, W1hT, W1lT, 512, 9, 511);
    wsplit_kernel<<<(512 * 256 + 255) / 256, 256, 0, stream>>>(W2, W2hT, W2lT, 512, 8, 255);
    weconv_kernel<<<(8 * 40 * 512 + 255) / 256, 256, 0, stream>>>(We, We_h, 8 * 40 * 512);

    // ---- layer 1 (two M-halves so A-pair fits aliased workspace) ----
    const int waves_half = (half * 64 + 255) / 256;
    for (int h = 0; h < 2; ++h) {
        agg512_kernel<<<waves_half, 256, 0, stream>>>(x, ssrc, offsets, dinv,
                                                      A1h, A2h, h * half, half);
        dim3 g1(512 / 128, (half + 127) / 128);
        gemm_split_kernel<1><<<g1, 256, 0, stream>>>(
            A1h, A2h, W1hT, W1lT, b1,
            B1 + (size_t)h * half * 512, B2 + (size_t)h * half * 512, nullptr,
            half, 512, 512, 512);
    }

    // ---- layer 2 GEMM: t = h1 @ W2 (fp32 out, aliases A region) ----
    dim3 g2(256 / 128, (n + 127) / 128);
    gemm_split_kernel<0><<<g2, 256, 0, stream>>>(
        B1, B2, W2hT, W2lT, nullptr, nullptr, nullptr, t, n, 256, 512, 256);

    // ---- layer 2 aggregation -> xc[:,0:256] + fp16 copy ----
    const int waves_grid = (n * 64 + 255) / 256;
    agg256_kernel<<<waves_grid, 256, 0, stream>>>(t, ssrc, offsets, dinv, b2, xc, h2h, n);

    // ---- fused neighbor-mean + MoE head ----
    mean_expert_kernel<<<waves_grid, 256, 0, stream>>>(ssrc, offsets, Wp, We_h, h2h, xc, out, n);
}

// Round 4
// 1515.149 us; speedup vs baseline: 1.2792x; 1.0109x over previous
//
#include <hip/hip_runtime.h>
#include <hip/hip_bf16.h>
#include <hip/hip_fp16.h>
#include <cstdint>
#include <cstddef>

// ---------------------------------------------------------------------------
// ROGPL_79517024518975: 2-layer GCN + mean-aggr + prototype-routed MoE head.
// Round 4:
//  - GEMMs via split-bf16 MFMA, 3-term (Ah*Bh + Ah*Bl + Al*Bh; Al*Bl ~1e-6
//    relative, dropped), fp32 accumulate.
//  - Head restructured: 16-lane reduction groups x 4 concurrent classes,
//    xc row staged in LDS (fp32 for scores, fp16 for expert fdot2 path).
//    Scores/argmax stay fp32; post-argmax expert dots use v_dot2_f32_f16.
//  - Gathers unchanged (near random-row L2/L3 service ceiling ~7 TB/s).
// ---------------------------------------------------------------------------

using short8 = __attribute__((ext_vector_type(8))) short;
using f32x4  = __attribute__((ext_vector_type(4))) float;
typedef _Float16 half2_t __attribute__((ext_vector_type(2)));

#define GLB_AS __attribute__((address_space(1)))
#define LDS_AS __attribute__((address_space(3)))

#if defined(__has_builtin)
# if __has_builtin(__builtin_amdgcn_fdot2)
#  define HAVE_FDOT2 1
# endif
#endif

// acc += dot(2 packed halfs in a, 2 packed halfs in b), fp32 accumulate
__device__ inline float dot2acc(float a, float b, float acc) {
#ifdef HAVE_FDOT2
    return __builtin_amdgcn_fdot2(__builtin_bit_cast(half2_t, a),
                                  __builtin_bit_cast(half2_t, b), acc, false);
#else
    const __half2 ha = __builtin_bit_cast(__half2, a);
    const __half2 hb = __builtin_bit_cast(__half2, b);
    const float2 fa = __half22float2(ha);
    const float2 fb = __half22float2(hb);
    return fmaf(fa.y, fb.y, fmaf(fa.x, fb.x, acc));
#endif
}

__device__ inline ushort f2bf_rne(float v) {
    uint32_t u = __builtin_bit_cast(uint32_t, v);
    uint32_t r = (u + 0x7FFFu + ((u >> 16) & 1u)) >> 16;
    return (ushort)r;
}
__device__ inline float bf2f(ushort b) {
    uint32_t u = ((uint32_t)b) << 16;
    return __builtin_bit_cast(float, u);
}
__device__ inline void split1(float v, ushort& hi, ushort& lo) {
    hi = f2bf_rne(v);
    lo = f2bf_rne(v - bf2f(hi));
}

// ---------------- CSR build ------------------------------------------------
__global__ void hist_kernel(const int* __restrict__ dst, int* __restrict__ counts, int e) {
    int i = blockIdx.x * blockDim.x + threadIdx.x;
    if (i < e) atomicAdd(&counts[dst[i]], 1);
}

__global__ __launch_bounds__(1024) void scan_kernel(const int* __restrict__ counts,
                                                    int* __restrict__ offsets,
                                                    int* __restrict__ cursor,
                                                    float* __restrict__ dinv,
                                                    int n, int e) {
    __shared__ int sdata[1024];
    const int t = threadIdx.x;
    const int chunk = (n + 1023) / 1024;
    const int beg = t * chunk;
    const int end = min(beg + chunk, n);
    int s = 0;
    for (int j = beg; j < end; ++j) s += counts[j];
    sdata[t] = s;
    __syncthreads();
    for (int off = 1; off < 1024; off <<= 1) {
        int v = (t >= off) ? sdata[t - off] : 0;
        __syncthreads();
        sdata[t] += v;
        __syncthreads();
    }
    int run = sdata[t] - s;
    for (int j = beg; j < end; ++j) {
        int c = counts[j];
        offsets[j] = run;
        cursor[j]  = run;
        dinv[j] = rsqrtf((float)c + 1.0f);  // deg includes self-loop
        run += c;
    }
    if (t == 0) offsets[n] = e;
}

__global__ void scatter_kernel(const int* __restrict__ src, const int* __restrict__ dst,
                               int* __restrict__ cursor, int* __restrict__ ssrc, int e) {
    int i = blockIdx.x * blockDim.x + threadIdx.x;
    if (i < e) {
        int d = dst[i];
        int pos = atomicAdd(&cursor[d], 1);
        ssrc[pos] = src[i];
    }
}

// ---------------- weight preparation --------------------------------------
__global__ void wsplit_kernel(const float* __restrict__ W, ushort* __restrict__ WhT,
                              ushort* __restrict__ WlT, int K, int nshift, int nmask) {
    int gid = blockIdx.x * blockDim.x + threadIdx.x;
    if (gid >= (K << nshift)) return;
    int k = gid >> nshift;
    int nn = gid & nmask;
    ushort hi, lo;
    split1(W[gid], hi, lo);
    WhT[(size_t)nn * K + k] = hi;
    WlT[(size_t)nn * K + k] = lo;
}

__global__ void weconv_kernel(const float* __restrict__ We, __half* __restrict__ We_h, int total) {
    int gid = blockIdx.x * blockDim.x + threadIdx.x;
    if (gid < total) We_h[gid] = __float2half(We[gid]);
}

// ---------------- wave-per-node aggregations -------------------------------
__global__ __launch_bounds__(256) void agg512_kernel(const float* __restrict__ x,
                                                     const int* __restrict__ ssrc,
                                                     const int* __restrict__ offsets,
                                                     const float* __restrict__ dinv,
                                                     ushort* __restrict__ A1,
                                                     ushort* __restrict__ A2,
                                                     int base, int cnt) {
    const int lane = threadIdx.x & 63;
    const int local = (blockIdx.x * blockDim.x + threadIdx.x) >> 6;
    if (local >= cnt) return;
    const int node = base + local;
    const int beg = offsets[node], end = offsets[node + 1];
    const float di = dinv[node];
    const int c0 = lane * 4;
    float4 acc0 = make_float4(0.f, 0.f, 0.f, 0.f);
    float4 acc1 = make_float4(0.f, 0.f, 0.f, 0.f);
    for (int b0 = beg; b0 < end; b0 += 64) {
        const int idx = b0 + lane;
        const int sl = (idx < end) ? ssrc[idx] : 0;
        const float wl = (idx < end) ? di * dinv[sl] : 0.f;
        const int m = min(64, end - b0);
#pragma unroll 8
        for (int k = 0; k < m; ++k) {
            const int s = __shfl(sl, k);
            const float w = __shfl(wl, k);
            const float* r = &x[(size_t)s * 512];
            const float4 v0 = *(const float4*)&r[c0];
            const float4 v1 = *(const float4*)&r[c0 + 256];
            acc0.x = fmaf(w, v0.x, acc0.x); acc0.y = fmaf(w, v0.y, acc0.y);
            acc0.z = fmaf(w, v0.z, acc0.z); acc0.w = fmaf(w, v0.w, acc0.w);
            acc1.x = fmaf(w, v1.x, acc1.x); acc1.y = fmaf(w, v1.y, acc1.y);
            acc1.z = fmaf(w, v1.z, acc1.z); acc1.w = fmaf(w, v1.w, acc1.w);
        }
    }
    {   // self-loop
        const float w = di * di;
        const float* r = &x[(size_t)node * 512];
        const float4 v0 = *(const float4*)&r[c0];
        const float4 v1 = *(const float4*)&r[c0 + 256];
        acc0.x = fmaf(w, v0.x, acc0.x); acc0.y = fmaf(w, v0.y, acc0.y);
        acc0.z = fmaf(w, v0.z, acc0.z); acc0.w = fmaf(w, v0.w, acc0.w);
        acc1.x = fmaf(w, v1.x, acc1.x); acc1.y = fmaf(w, v1.y, acc1.y);
        acc1.z = fmaf(w, v1.z, acc1.z); acc1.w = fmaf(w, v1.w, acc1.w);
    }
    ushort4 h0, l0, h1v, l1v;
    split1(acc0.x, h0.x, l0.x); split1(acc0.y, h0.y, l0.y);
    split1(acc0.z, h0.z, l0.z); split1(acc0.w, h0.w, l0.w);
    split1(acc1.x, h1v.x, l1v.x); split1(acc1.y, h1v.y, l1v.y);
    split1(acc1.z, h1v.z, l1v.z); split1(acc1.w, h1v.w, l1v.w);
    const size_t r = (size_t)local * 512;
    *(ushort4*)&A1[r + c0] = h0;       *(ushort4*)&A1[r + 256 + c0] = h1v;
    *(ushort4*)&A2[r + c0] = l0;       *(ushort4*)&A2[r + 256 + c0] = l1v;
}

__global__ __launch_bounds__(256) void agg256_kernel(const float* __restrict__ t,
                                                     const int* __restrict__ ssrc,
                                                     const int* __restrict__ offsets,
                                                     const float* __restrict__ dinv,
                                                     const float* __restrict__ bias,
                                                     float* __restrict__ xc,
                                                     __half* __restrict__ h2h, int n) {
    const int lane = threadIdx.x & 63;
    const int node = (blockIdx.x * blockDim.x + threadIdx.x) >> 6;
    if (node >= n) return;
    const int beg = offsets[node], end = offsets[node + 1];
    const float di = dinv[node];
    const int c0 = lane * 4;
    float4 acc = make_float4(0.f, 0.f, 0.f, 0.f);
    for (int b0 = beg; b0 < end; b0 += 64) {
        const int idx = b0 + lane;
        const int sl = (idx < end) ? ssrc[idx] : 0;
        const float wl = (idx < end) ? di * dinv[sl] : 0.f;
        const int m = min(64, end - b0);
#pragma unroll 8
        for (int k = 0; k < m; ++k) {
            const int s = __shfl(sl, k);
            const float w = __shfl(wl, k);
            const float4 v = *(const float4*)&t[(size_t)s * 256 + c0];
            acc.x = fmaf(w, v.x, acc.x); acc.y = fmaf(w, v.y, acc.y);
            acc.z = fmaf(w, v.z, acc.z); acc.w = fmaf(w, v.w, acc.w);
        }
    }
    {   // self-loop + bias
        const float w = di * di;
        const float4 v = *(const float4*)&t[(size_t)node * 256 + c0];
        const float4 bv = *(const float4*)&bias[c0];
        acc.x = fmaf(w, v.x, acc.x) + bv.x;
        acc.y = fmaf(w, v.y, acc.y) + bv.y;
        acc.z = fmaf(w, v.z, acc.z) + bv.z;
        acc.w = fmaf(w, v.w, acc.w) + bv.w;
    }
    *(float4*)&xc[(size_t)node * 512 + c0] = acc;
    __half2 q01 = __floats2half2_rn(acc.x, acc.y);
    __half2 q23 = __floats2half2_rn(acc.z, acc.w);
    float2 pk;
    *(__half2*)&pk.x = q01;
    *(__half2*)&pk.y = q23;
    *(float2*)&h2h[(size_t)node * 256 + c0] = pk;
}

// ---------------- split-bf16 MFMA GEMM (3-term) ----------------------------
template <int EPI>
__global__ __launch_bounds__(256) void gemm_split_kernel(
    const ushort* __restrict__ Ah, const ushort* __restrict__ Al,
    const ushort* __restrict__ WhT, const ushort* __restrict__ WlT,
    const float* __restrict__ bias,
    ushort* __restrict__ Ch, ushort* __restrict__ Cl,
    float* __restrict__ Cf,
    int M, int N, int K, int ldc) {
    __shared__ ushort smem[4 * 4096];  // Ah | Al | WhT | WlT tiles, each 128x32 bf16
    const int tid = threadIdx.x;
    const int lane = tid & 63;
    const int w = tid >> 6;
    const int wr = w >> 1, wc = w & 1;
    const int bm = blockIdx.y * 128;
    const int bn = blockIdx.x * 128;

    f32x4 acc[4][4];
#pragma unroll
    for (int i = 0; i < 4; ++i)
#pragma unroll
        for (int j = 0; j < 4; ++j) acc[i][j] = f32x4{0.f, 0.f, 0.f, 0.f};

    const ushort* sbase = (w == 0) ? Ah : (w == 1) ? Al : (w == 2) ? WhT : WlT;
    const int rowbase = (w < 2) ? bm : bn;
    const int rowmax = (w < 2) ? (M - 1) : (N - 1);

    for (int k0 = 0; k0 < K; k0 += 32) {
        __syncthreads();
#pragma unroll
        for (int i = 0; i < 8; ++i) {
            const int c = i * 64 + lane;
            int row = rowbase + (c >> 2);
            row = min(row, rowmax);
            const ushort* g = sbase + (size_t)row * K + k0 + (c & 3) * 8;
            __builtin_amdgcn_global_load_lds((const GLB_AS void*)g,
                                             (LDS_AS void*)(smem + w * 4096 + i * 512),
                                             16, 0, 0);
        }
        __syncthreads();

        const int koff = (lane >> 4) * 8;
        const int rsel = lane & 15;
        short8 a1[4], a2[4], b1[4], b2[4];
#pragma unroll
        for (int f = 0; f < 4; ++f) {
            const int ar = wr * 64 + f * 16 + rsel;
            a1[f] = *(const short8*)&smem[0 * 4096 + ar * 32 + koff];
            a2[f] = *(const short8*)&smem[1 * 4096 + ar * 32 + koff];
            const int bc = wc * 64 + f * 16 + rsel;
            b1[f] = *(const short8*)&smem[2 * 4096 + bc * 32 + koff];
            b2[f] = *(const short8*)&smem[3 * 4096 + bc * 32 + koff];
        }
        // 3-term: Ah*Bh + Ah*Bl + Al*Bh (Al*Bl ~1e-6 relative, dropped)
#pragma unroll
        for (int i = 0; i < 4; ++i)
#pragma unroll
            for (int j = 0; j < 4; ++j) {
                acc[i][j] = __builtin_amdgcn_mfma_f32_16x16x32_bf16(a1[i], b1[j], acc[i][j], 0, 0, 0);
                acc[i][j] = __builtin_amdgcn_mfma_f32_16x16x32_bf16(a1[i], b2[j], acc[i][j], 0, 0, 0);
                acc[i][j] = __builtin_amdgcn_mfma_f32_16x16x32_bf16(a2[i], b1[j], acc[i][j], 0, 0, 0);
            }
    }

    const int crow0 = wr * 64 + (lane >> 4) * 4;
    const int ccol0 = wc * 64 + (lane & 15);
#pragma unroll
    for (int f = 0; f < 4; ++f) {
#pragma unroll
        for (int g = 0; g < 4; ++g) {
            const int colg = bn + ccol0 + g * 16;
            float bv = 0.f;
            if constexpr (EPI == 1) bv = bias[colg];
#pragma unroll
            for (int j = 0; j < 4; ++j) {
                const int rowg = bm + crow0 + f * 16 + j;
                if (rowg >= M) continue;
                float v = acc[f][g][j];
                if constexpr (EPI == 1) {
                    v = fmaxf(v + bv, 0.f);
                    ushort hi, lo;
                    split1(v, hi, lo);
                    Ch[(size_t)rowg * ldc + colg] = hi;
                    Cl[(size_t)rowg * ldc + colg] = lo;
                } else {
                    Cf[(size_t)rowg * ldc + colg] = v;
                }
            }
        }
    }
}

// ---------------- fused mean-aggregation + MoE head ------------------------
// One wave per node. Phase 1: mean gather (fp16 h2 rows) -> b; stage full xc
// row in LDS (fp32 + fp16). Phase 2: scores fp32, 16-lane groups, 4 classes
// in parallel; argmax. Phase 3: expert dots via v_dot2_f32_f16.
__global__ __launch_bounds__(256) void mean_expert_kernel(const int* __restrict__ ssrc,
                                                          const int* __restrict__ offsets,
                                                          const float* __restrict__ Wp,
                                                          const __half* __restrict__ We_h,
                                                          const __half* __restrict__ h2h,
                                                          float* __restrict__ xc,
                                                          float* __restrict__ out, int n) {
    __shared__ float  lds_f[4][512];
    __shared__ __half lds_h[4][512];
    const int lane = threadIdx.x & 63;
    const int w = threadIdx.x >> 6;
    const int node = (blockIdx.x * blockDim.x + threadIdx.x) >> 6;
    if (node >= n) return;
    const int beg = offsets[node], end = offsets[node + 1];
    const int c0 = lane * 4;

    // ---- phase 1: neighbor mean of h2 (fp16 rows) ----
    float4 b = make_float4(0.f, 0.f, 0.f, 0.f);
    for (int b0 = beg; b0 < end; b0 += 64) {
        const int idx = b0 + lane;
        const int sl = (idx < end) ? ssrc[idx] : 0;
        const int m = min(64, end - b0);
#pragma unroll 8
        for (int k = 0; k < m; ++k) {
            const int s = __shfl(sl, k);
            const float2 raw = *(const float2*)&h2h[(size_t)s * 256 + c0];
            const float2 f01 = __half22float2(*(const __half2*)&raw.x);
            const float2 f23 = __half22float2(*(const __half2*)&raw.y);
            b.x += f01.x; b.y += f01.y; b.z += f23.x; b.w += f23.y;
        }
    }
    const float inv = 1.f / fmaxf((float)(end - beg), 1.f);
    b.x *= inv; b.y *= inv; b.z *= inv; b.w *= inv;
    *(float4*)&xc[(size_t)node * 512 + 256 + c0] = b;
    const float4 a = *(const float4*)&xc[(size_t)node * 512 + c0];  // own h2 (fp32)

    // stage row to LDS: fp32 (scores) + fp16 (expert fdot2)
    *(float4*)&lds_f[w][c0] = a;
    *(float4*)&lds_f[w][256 + c0] = b;
    {
        __half2 a01 = __floats2half2_rn(a.x, a.y), a23 = __floats2half2_rn(a.z, a.w);
        __half2 b01 = __floats2half2_rn(b.x, b.y), b23 = __floats2half2_rn(b.z, b.w);
        float2 pa, pb;
        *(__half2*)&pa.x = a01; *(__half2*)&pa.y = a23;
        *(__half2*)&pb.x = b01; *(__half2*)&pb.y = b23;
        *(float2*)&lds_h[w][c0] = pa;
        *(float2*)&lds_h[w][256 + c0] = pb;
    }
    // wave-synchronous: same-wave DS ordering + compiler lgkmcnt waits suffice

    const int r = lane & 15;
    const int quad = lane >> 4;

    // ---- phase 2: scores (fp32), 4 classes concurrently, 16-lane reduce ----
    float av[32];
#pragma unroll
    for (int i = 0; i < 8; ++i)
        *(float4*)&av[i * 4] = *(const float4*)&lds_f[w][r * 32 + i * 4];

    float s0, s1;
#pragma unroll
    for (int t = 0; t < 2; ++t) {
        const int c = t * 4 + quad;
        const float* wp = &Wp[c * 512 + r * 32];
        float p = 0.f;
#pragma unroll
        for (int i = 0; i < 8; ++i) {
            const float4 wv = *(const float4*)&wp[i * 4];
            p = fmaf(av[i * 4 + 0], wv.x, p);
            p = fmaf(av[i * 4 + 1], wv.y, p);
            p = fmaf(av[i * 4 + 2], wv.z, p);
            p = fmaf(av[i * 4 + 3], wv.w, p);
        }
        p += __shfl_xor(p, 1); p += __shfl_xor(p, 2);
        p += __shfl_xor(p, 4); p += __shfl_xor(p, 8);
        if (t == 0) s0 = p; else s1 = p;
    }
    float best = -3.0e38f;
    int bidx = 0;
#pragma unroll
    for (int c = 0; c < 8; ++c) {  // class order: first-max tiebreak = argmax
        const float v = __shfl((c < 4) ? s0 : s1, (c & 3) * 16);
        if (v > best) { best = v; bidx = c; }
    }

    // ---- phase 3: expert dots (fp16 x fp16, fp32 accum via fdot2) ----
    float4 ah[4];  // this lane's 32 halfs of the xc row
#pragma unroll
    for (int i = 0; i < 4; ++i)
        ah[i] = *(const float4*)&lds_h[w][r * 32 + i * 8];

    const __half* web = We_h + (size_t)bidx * 40 * 512;
#pragma unroll
    for (int t = 0; t < 10; ++t) {
        const int c = t * 4 + quad;
        const __half* wr_ = web + c * 512 + r * 32;
        float p = 0.f;
#pragma unroll
        for (int i = 0; i < 4; ++i) {
            const float4 wv = *(const float4*)&wr_[i * 8];
            p = dot2acc(ah[i].x, wv.x, p);
            p = dot2acc(ah[i].y, wv.y, p);
            p = dot2acc(ah[i].z, wv.z, p);
            p = dot2acc(ah[i].w, wv.w, p);
        }
        p += __shfl_xor(p, 1); p += __shfl_xor(p, 2);
        p += __shfl_xor(p, 4); p += __shfl_xor(p, 8);
        if (r == 0) out[(size_t)node * 40 + c] = p;
    }
}

extern "C" void kernel_launch(void* const* d_in, const int* in_sizes, int n_in,
                              void* d_out, int out_size, void* d_ws, size_t ws_size,
                              hipStream_t stream) {
    const float* x  = (const float*)d_in[0];
    const int*  edge = (const int*)d_in[1];
    const float* W1 = (const float*)d_in[2];
    const float* b1 = (const float*)d_in[3];
    const float* W2 = (const float*)d_in[4];
    const float* b2 = (const float*)d_in[5];
    const float* Wp = (const float*)d_in[6];
    const float* We = (const float*)d_in[7];

    const int n = in_sizes[0] / 512;   // 50000
    const int e = in_sizes[1] / 2;     // 1600000
    const int half = n / 2;            // 25000
    const int* src = edge;
    const int* dst = edge + e;

    // ---- workspace layout (peak ~163 MB; aliasing documented) ----
    char* ws = (char*)d_ws;
    ushort* A1h = (ushort*)ws;                             // [half,512] bf16 hi
    ushort* A2h = (ushort*)(ws + (size_t)half * 512 * 2);  // [half,512] bf16 lo
    float*  t   = (float*)ws;                              // [n,256] fp32 (aliases A, after GEMM1)
    char* p = ws + (size_t)n * 512 * 2;
    ushort* B1 = (ushort*)p; p += (size_t)n * 512 * 2;     // [n,512] h1 hi
    __half* h2h = (__half*)B1;                             // [n,256] fp16 (aliases B1, after GEMM2)
    ushort* B2 = (ushort*)p; p += (size_t)n * 512 * 2;     // [n,512] h1 lo
    ushort* W1hT = (ushort*)p; p += 512 * 512 * 2;
    ushort* W1lT = (ushort*)p; p += 512 * 512 * 2;
    ushort* W2hT = (ushort*)p; p += 256 * 512 * 2;
    ushort* W2lT = (ushort*)p; p += 256 * 512 * 2;
    __half* We_h = (__half*)p; p += 8 * 40 * 512 * 2;
    auto align16 = [](size_t v) { return (v + 15) & ~(size_t)15; };
    float* dinv = (float*)p;    p += align16((size_t)n * 4);
    int* counts = (int*)p;      p += align16((size_t)n * 4);
    int* offsets = (int*)p;     p += align16((size_t)(n + 1) * 4);
    int* cursor = (int*)p;      p += align16((size_t)n * 4);
    int* ssrc = (int*)p;        // [e]

    float* out = (float*)d_out;                 // [n,40]
    float* xc = (float*)d_out + (size_t)n * 40; // [n,512]

    // ---- CSR build ----
    hipMemsetAsync(counts, 0, (size_t)n * 4, stream);
    hist_kernel<<<(e + 255) / 256, 256, 0, stream>>>(dst, counts, e);
    scan_kernel<<<1, 1024, 0, stream>>>(counts, offsets, cursor, dinv, n, e);
    scatter_kernel<<<(e + 255) / 256, 256, 0, stream>>>(src, dst, cursor, ssrc, e);

    // ---- weight prep ----
    wsplit_kernel<<<(512 * 512 + 255) / 256, 256, 0, stream>>>(W1, W1hT, W1lT, 512, 9, 511);
    wsplit_kernel<<<(512 * 256 + 255) / 256, 256, 0, stream>>>(W2, W2hT, W2lT, 512, 8, 255);
    weconv_kernel<<<(8 * 40 * 512 + 255) / 256, 256, 0, stream>>>(We, We_h, 8 * 40 * 512);

    // ---- layer 1 (two M-halves so A-pair fits aliased workspace) ----
    const int waves_half = (half * 64 + 255) / 256;
    for (int h = 0; h < 2; ++h) {
        agg512_kernel<<<waves_half, 256, 0, stream>>>(x, ssrc, offsets, dinv,
                                                      A1h, A2h, h * half, half);
        dim3 g1(512 / 128, (half + 127) / 128);
        gemm_split_kernel<1><<<g1, 256, 0, stream>>>(
            A1h, A2h, W1hT, W1lT, b1,
            B1 + (size_t)h * half * 512, B2 + (size_t)h * half * 512, nullptr,
            half, 512, 512, 512);
    }

    // ---- layer 2 GEMM: t = h1 @ W2 (fp32 out, aliases A region) ----
    dim3 g2(256 / 128, (n + 127) / 128);
    gemm_split_kernel<0><<<g2, 256, 0, stream>>>(
        B1, B2, W2hT, W2lT, nullptr, nullptr, nullptr, t, n, 256, 512, 256);

    // ---- layer 2 aggregation -> xc[:,0:256] + fp16 copy ----
    const int waves_grid = (n * 64 + 255) / 256;
    agg256_kernel<<<waves_grid, 256, 0, stream>>>(t, ssrc, offsets, dinv, b2, xc, h2h, n);

    // ---- fused neighbor-mean + MoE head ----
    mean_expert_kernel<<<waves_grid, 256, 0, stream>>>(ssrc, offsets, Wp, We_h, h2h, xc, out, n);
}

// Round 5
// 1491.848 us; speedup vs baseline: 1.2992x; 1.0156x over previous
//
#include <hip/hip_runtime.h>
#include <hip/hip_bf16.h>
#include <hip/hip_fp16.h>
#include <cstdint>
#include <cstddef>

// ---------------------------------------------------------------------------
// ROGPL_79517024518975: 2-layer GCN + mean-aggr + prototype-routed MoE head.
// Round 5:
//  - mean gather: 2 edges per wave (32 lanes x 16B per fp16 row) -> halves
//    per-edge VMEM instruction count (was latency-bound at 8B/lane).
//  - LDS rotation swizzle in head phases 2/3 kills 16-way/8-way bank
//    conflicts (1.36e7 conflict-cycles in R4).
//  - GEMMs: split-bf16 MFMA 3-term (unchanged from R4).
//  - agg512/agg256 unchanged (at ~7 TB/s random-row service ceiling).
// ---------------------------------------------------------------------------

using short8 = __attribute__((ext_vector_type(8))) short;
using f32x4  = __attribute__((ext_vector_type(4))) float;
typedef _Float16 half2_t __attribute__((ext_vector_type(2)));

#define GLB_AS __attribute__((address_space(1)))
#define LDS_AS __attribute__((address_space(3)))

#if defined(__has_builtin)
# if __has_builtin(__builtin_amdgcn_fdot2)
#  define HAVE_FDOT2 1
# endif
#endif

__device__ inline float dot2acc(float a, float b, float acc) {
#ifdef HAVE_FDOT2
    return __builtin_amdgcn_fdot2(__builtin_bit_cast(half2_t, a),
                                  __builtin_bit_cast(half2_t, b), acc, false);
#else
    const __half2 ha = __builtin_bit_cast(__half2, a);
    const __half2 hb = __builtin_bit_cast(__half2, b);
    const float2 fa = __half22float2(ha);
    const float2 fb = __half22float2(hb);
    return fmaf(fa.y, fb.y, fmaf(fa.x, fb.x, acc));
#endif
}

__device__ inline ushort f2bf_rne(float v) {
    uint32_t u = __builtin_bit_cast(uint32_t, v);
    uint32_t r = (u + 0x7FFFu + ((u >> 16) & 1u)) >> 16;
    return (ushort)r;
}
__device__ inline float bf2f(ushort b) {
    uint32_t u = ((uint32_t)b) << 16;
    return __builtin_bit_cast(float, u);
}
__device__ inline void split1(float v, ushort& hi, ushort& lo) {
    hi = f2bf_rne(v);
    lo = f2bf_rne(v - bf2f(hi));
}

// ---------------- CSR build ------------------------------------------------
__global__ void hist_kernel(const int* __restrict__ dst, int* __restrict__ counts, int e) {
    int i = blockIdx.x * blockDim.x + threadIdx.x;
    if (i < e) atomicAdd(&counts[dst[i]], 1);
}

__global__ __launch_bounds__(1024) void scan_kernel(const int* __restrict__ counts,
                                                    int* __restrict__ offsets,
                                                    int* __restrict__ cursor,
                                                    float* __restrict__ dinv,
                                                    int n, int e) {
    __shared__ int sdata[1024];
    const int t = threadIdx.x;
    const int chunk = (n + 1023) / 1024;
    const int beg = t * chunk;
    const int end = min(beg + chunk, n);
    int s = 0;
    for (int j = beg; j < end; ++j) s += counts[j];
    sdata[t] = s;
    __syncthreads();
    for (int off = 1; off < 1024; off <<= 1) {
        int v = (t >= off) ? sdata[t - off] : 0;
        __syncthreads();
        sdata[t] += v;
        __syncthreads();
    }
    int run = sdata[t] - s;
    for (int j = beg; j < end; ++j) {
        int c = counts[j];
        offsets[j] = run;
        cursor[j]  = run;
        dinv[j] = rsqrtf((float)c + 1.0f);  // deg includes self-loop
        run += c;
    }
    if (t == 0) offsets[n] = e;
}

__global__ void scatter_kernel(const int* __restrict__ src, const int* __restrict__ dst,
                               int* __restrict__ cursor, int* __restrict__ ssrc, int e) {
    int i = blockIdx.x * blockDim.x + threadIdx.x;
    if (i < e) {
        int d = dst[i];
        int pos = atomicAdd(&cursor[d], 1);
        ssrc[pos] = src[i];
    }
}

// ---------------- weight preparation --------------------------------------
__global__ void wsplit_kernel(const float* __restrict__ W, ushort* __restrict__ WhT,
                              ushort* __restrict__ WlT, int K, int nshift, int nmask) {
    int gid = blockIdx.x * blockDim.x + threadIdx.x;
    if (gid >= (K << nshift)) return;
    int k = gid >> nshift;
    int nn = gid & nmask;
    ushort hi, lo;
    split1(W[gid], hi, lo);
    WhT[(size_t)nn * K + k] = hi;
    WlT[(size_t)nn * K + k] = lo;
}

__global__ void weconv_kernel(const float* __restrict__ We, __half* __restrict__ We_h, int total) {
    int gid = blockIdx.x * blockDim.x + threadIdx.x;
    if (gid < total) We_h[gid] = __float2half(We[gid]);
}

// ---------------- wave-per-node aggregations -------------------------------
__global__ __launch_bounds__(256) void agg512_kernel(const float* __restrict__ x,
                                                     const int* __restrict__ ssrc,
                                                     const int* __restrict__ offsets,
                                                     const float* __restrict__ dinv,
                                                     ushort* __restrict__ A1,
                                                     ushort* __restrict__ A2,
                                                     int base, int cnt) {
    const int lane = threadIdx.x & 63;
    const int local = (blockIdx.x * blockDim.x + threadIdx.x) >> 6;
    if (local >= cnt) return;
    const int node = base + local;
    const int beg = offsets[node], end = offsets[node + 1];
    const float di = dinv[node];
    const int c0 = lane * 4;
    float4 acc0 = make_float4(0.f, 0.f, 0.f, 0.f);
    float4 acc1 = make_float4(0.f, 0.f, 0.f, 0.f);
    for (int b0 = beg; b0 < end; b0 += 64) {
        const int idx = b0 + lane;
        const int sl = (idx < end) ? ssrc[idx] : 0;
        const float wl = (idx < end) ? di * dinv[sl] : 0.f;
        const int m = min(64, end - b0);
#pragma unroll 8
        for (int k = 0; k < m; ++k) {
            const int s = __shfl(sl, k);
            const float w = __shfl(wl, k);
            const float* r = &x[(size_t)s * 512];
            const float4 v0 = *(const float4*)&r[c0];
            const float4 v1 = *(const float4*)&r[c0 + 256];
            acc0.x = fmaf(w, v0.x, acc0.x); acc0.y = fmaf(w, v0.y, acc0.y);
            acc0.z = fmaf(w, v0.z, acc0.z); acc0.w = fmaf(w, v0.w, acc0.w);
            acc1.x = fmaf(w, v1.x, acc1.x); acc1.y = fmaf(w, v1.y, acc1.y);
            acc1.z = fmaf(w, v1.z, acc1.z); acc1.w = fmaf(w, v1.w, acc1.w);
        }
    }
    {   // self-loop
        const float w = di * di;
        const float* r = &x[(size_t)node * 512];
        const float4 v0 = *(const float4*)&r[c0];
        const float4 v1 = *(const float4*)&r[c0 + 256];
        acc0.x = fmaf(w, v0.x, acc0.x); acc0.y = fmaf(w, v0.y, acc0.y);
        acc0.z = fmaf(w, v0.z, acc0.z); acc0.w = fmaf(w, v0.w, acc0.w);
        acc1.x = fmaf(w, v1.x, acc1.x); acc1.y = fmaf(w, v1.y, acc1.y);
        acc1.z = fmaf(w, v1.z, acc1.z); acc1.w = fmaf(w, v1.w, acc1.w);
    }
    ushort4 h0, l0, h1v, l1v;
    split1(acc0.x, h0.x, l0.x); split1(acc0.y, h0.y, l0.y);
    split1(acc0.z, h0.z, l0.z); split1(acc0.w, h0.w, l0.w);
    split1(acc1.x, h1v.x, l1v.x); split1(acc1.y, h1v.y, l1v.y);
    split1(acc1.z, h1v.z, l1v.z); split1(acc1.w, h1v.w, l1v.w);
    const size_t r = (size_t)local * 512;
    *(ushort4*)&A1[r + c0] = h0;       *(ushort4*)&A1[r + 256 + c0] = h1v;
    *(ushort4*)&A2[r + c0] = l0;       *(ushort4*)&A2[r + 256 + c0] = l1v;
}

__global__ __launch_bounds__(256) void agg256_kernel(const float* __restrict__ t,
                                                     const int* __restrict__ ssrc,
                                                     const int* __restrict__ offsets,
                                                     const float* __restrict__ dinv,
                                                     const float* __restrict__ bias,
                                                     float* __restrict__ xc,
                                                     __half* __restrict__ h2h, int n) {
    const int lane = threadIdx.x & 63;
    const int node = (blockIdx.x * blockDim.x + threadIdx.x) >> 6;
    if (node >= n) return;
    const int beg = offsets[node], end = offsets[node + 1];
    const float di = dinv[node];
    const int c0 = lane * 4;
    float4 acc = make_float4(0.f, 0.f, 0.f, 0.f);
    for (int b0 = beg; b0 < end; b0 += 64) {
        const int idx = b0 + lane;
        const int sl = (idx < end) ? ssrc[idx] : 0;
        const float wl = (idx < end) ? di * dinv[sl] : 0.f;
        const int m = min(64, end - b0);
#pragma unroll 8
        for (int k = 0; k < m; ++k) {
            const int s = __shfl(sl, k);
            const float w = __shfl(wl, k);
            const float4 v = *(const float4*)&t[(size_t)s * 256 + c0];
            acc.x = fmaf(w, v.x, acc.x); acc.y = fmaf(w, v.y, acc.y);
            acc.z = fmaf(w, v.z, acc.z); acc.w = fmaf(w, v.w, acc.w);
        }
    }
    {   // self-loop + bias
        const float w = di * di;
        const float4 v = *(const float4*)&t[(size_t)node * 256 + c0];
        const float4 bv = *(const float4*)&bias[c0];
        acc.x = fmaf(w, v.x, acc.x) + bv.x;
        acc.y = fmaf(w, v.y, acc.y) + bv.y;
        acc.z = fmaf(w, v.z, acc.z) + bv.z;
        acc.w = fmaf(w, v.w, acc.w) + bv.w;
    }
    *(float4*)&xc[(size_t)node * 512 + c0] = acc;
    __half2 q01 = __floats2half2_rn(acc.x, acc.y);
    __half2 q23 = __floats2half2_rn(acc.z, acc.w);
    float2 pk;
    *(__half2*)&pk.x = q01;
    *(__half2*)&pk.y = q23;
    *(float2*)&h2h[(size_t)node * 256 + c0] = pk;
}

// ---------------- split-bf16 MFMA GEMM (3-term) ----------------------------
template <int EPI>
__global__ __launch_bounds__(256) void gemm_split_kernel(
    const ushort* __restrict__ Ah, const ushort* __restrict__ Al,
    const ushort* __restrict__ WhT, const ushort* __restrict__ WlT,
    const float* __restrict__ bias,
    ushort* __restrict__ Ch, ushort* __restrict__ Cl,
    float* __restrict__ Cf,
    int M, int N, int K, int ldc) {
    __shared__ ushort smem[4 * 4096];  // Ah | Al | WhT | WlT tiles, each 128x32 bf16
    const int tid = threadIdx.x;
    const int lane = tid & 63;
    const int w = tid >> 6;
    const int wr = w >> 1, wc = w & 1;
    const int bm = blockIdx.y * 128;
    const int bn = blockIdx.x * 128;

    f32x4 acc[4][4];
#pragma unroll
    for (int i = 0; i < 4; ++i)
#pragma unroll
        for (int j = 0; j < 4; ++j) acc[i][j] = f32x4{0.f, 0.f, 0.f, 0.f};

    const ushort* sbase = (w == 0) ? Ah : (w == 1) ? Al : (w == 2) ? WhT : WlT;
    const int rowbase = (w < 2) ? bm : bn;
    const int rowmax = (w < 2) ? (M - 1) : (N - 1);

    for (int k0 = 0; k0 < K; k0 += 32) {
        __syncthreads();
#pragma unroll
        for (int i = 0; i < 8; ++i) {
            const int c = i * 64 + lane;
            int row = rowbase + (c >> 2);
            row = min(row, rowmax);
            const ushort* g = sbase + (size_t)row * K + k0 + (c & 3) * 8;
            __builtin_amdgcn_global_load_lds((const GLB_AS void*)g,
                                             (LDS_AS void*)(smem + w * 4096 + i * 512),
                                             16, 0, 0);
        }
        __syncthreads();

        const int koff = (lane >> 4) * 8;
        const int rsel = lane & 15;
        short8 a1[4], a2[4], b1[4], b2[4];
#pragma unroll
        for (int f = 0; f < 4; ++f) {
            const int ar = wr * 64 + f * 16 + rsel;
            a1[f] = *(const short8*)&smem[0 * 4096 + ar * 32 + koff];
            a2[f] = *(const short8*)&smem[1 * 4096 + ar * 32 + koff];
            const int bc = wc * 64 + f * 16 + rsel;
            b1[f] = *(const short8*)&smem[2 * 4096 + bc * 32 + koff];
            b2[f] = *(const short8*)&smem[3 * 4096 + bc * 32 + koff];
        }
        // 3-term: Ah*Bh + Ah*Bl + Al*Bh (Al*Bl ~1e-6 relative, dropped)
#pragma unroll
        for (int i = 0; i < 4; ++i)
#pragma unroll
            for (int j = 0; j < 4; ++j) {
                acc[i][j] = __builtin_amdgcn_mfma_f32_16x16x32_bf16(a1[i], b1[j], acc[i][j], 0, 0, 0);
                acc[i][j] = __builtin_amdgcn_mfma_f32_16x16x32_bf16(a1[i], b2[j], acc[i][j], 0, 0, 0);
                acc[i][j] = __builtin_amdgcn_mfma_f32_16x16x32_bf16(a2[i], b1[j], acc[i][j], 0, 0, 0);
            }
    }

    const int crow0 = wr * 64 + (lane >> 4) * 4;
    const int ccol0 = wc * 64 + (lane & 15);
#pragma unroll
    for (int f = 0; f < 4; ++f) {
#pragma unroll
        for (int g = 0; g < 4; ++g) {
            const int colg = bn + ccol0 + g * 16;
            float bv = 0.f;
            if constexpr (EPI == 1) bv = bias[colg];
#pragma unroll
            for (int j = 0; j < 4; ++j) {
                const int rowg = bm + crow0 + f * 16 + j;
                if (rowg >= M) continue;
                float v = acc[f][g][j];
                if constexpr (EPI == 1) {
                    v = fmaxf(v + bv, 0.f);
                    ushort hi, lo;
                    split1(v, hi, lo);
                    Ch[(size_t)rowg * ldc + colg] = hi;
                    Cl[(size_t)rowg * ldc + colg] = lo;
                } else {
                    Cf[(size_t)rowg * ldc + colg] = v;
                }
            }
        }
    }
}

// ---------------- fused mean-aggregation + MoE head ------------------------
// One wave per node.
// Phase 1: mean gather, 2 edges per wave: half-wave h (32 lanes x 16B) reads
//   edge k=kp+h; fp32 accumulate of 8 cols per lane; combine via shfl.
// Phase 2: scores fp32 from LDS (rotation-swizzled reads), 16-lane groups x
//   4 classes; argmax. Phase 3: expert dots via fdot2 (rotation-swizzled).
__global__ __launch_bounds__(256) void mean_expert_kernel(const int* __restrict__ ssrc,
                                                          const int* __restrict__ offsets,
                                                          const float* __restrict__ Wp,
                                                          const __half* __restrict__ We_h,
                                                          const __half* __restrict__ h2h,
                                                          float* __restrict__ xc,
                                                          float* __restrict__ out, int n) {
    __shared__ float  lds_f[4][512];
    __shared__ __half lds_h[4][512];
    const int lane = threadIdx.x & 63;
    const int w = threadIdx.x >> 6;
    const int node = (blockIdx.x * blockDim.x + threadIdx.x) >> 6;
    if (node >= n) return;
    const int beg = offsets[node], end = offsets[node + 1];
    const int c0 = lane * 4;
    const int half = lane >> 5;   // which edge of the pair
    const int hl = lane & 31;     // lane within half-wave; owns cols [hl*8, hl*8+8)

    // ---- phase 1: neighbor mean of h2 (fp16 rows), 2 rows per wave-instr ----
    float acc8[8] = {0.f, 0.f, 0.f, 0.f, 0.f, 0.f, 0.f, 0.f};
    for (int b0 = beg; b0 < end; b0 += 64) {
        const int idx = b0 + lane;
        const int sl = (idx < end) ? ssrc[idx] : 0;
        const int m = min(64, end - b0);
#pragma unroll 8
        for (int kp = 0; kp < m; kp += 2) {
            const int k = kp + half;
            const int s = __shfl(sl, k);
            float4 raw = make_float4(0.f, 0.f, 0.f, 0.f);
            if (k < m) raw = *(const float4*)&h2h[(size_t)s * 256 + hl * 8];
            const float2 f0 = __half22float2(*(const __half2*)&raw.x);
            const float2 f1 = __half22float2(*(const __half2*)&raw.y);
            const float2 f2 = __half22float2(*(const __half2*)&raw.z);
            const float2 f3 = __half22float2(*(const __half2*)&raw.w);
            acc8[0] += f0.x; acc8[1] += f0.y; acc8[2] += f1.x; acc8[3] += f1.y;
            acc8[4] += f2.x; acc8[5] += f2.y; acc8[6] += f3.x; acc8[7] += f3.y;
        }
    }
    // combine the two half-wave partials (lanes 0-31 get lane+32's partial)
#pragma unroll
    for (int j = 0; j < 8; ++j) acc8[j] += __shfl(acc8[j], hl + 32);

    const float inv = 1.f / fmaxf((float)(end - beg), 1.f);
    if (half == 0) {
        float4 b0v = make_float4(acc8[0] * inv, acc8[1] * inv, acc8[2] * inv, acc8[3] * inv);
        float4 b1v = make_float4(acc8[4] * inv, acc8[5] * inv, acc8[6] * inv, acc8[7] * inv);
        *(float4*)&xc[(size_t)node * 512 + 256 + hl * 8] = b0v;
        *(float4*)&xc[(size_t)node * 512 + 256 + hl * 8 + 4] = b1v;
        *(float4*)&lds_f[w][256 + hl * 8] = b0v;
        *(float4*)&lds_f[w][256 + hl * 8 + 4] = b1v;
        __half2 q0 = __floats2half2_rn(b0v.x, b0v.y), q1 = __floats2half2_rn(b0v.z, b0v.w);
        __half2 q2 = __floats2half2_rn(b1v.x, b1v.y), q3 = __floats2half2_rn(b1v.z, b1v.w);
        float4 pk;
        *(__half2*)&pk.x = q0; *(__half2*)&pk.y = q1;
        *(__half2*)&pk.z = q2; *(__half2*)&pk.w = q3;
        *(float4*)&lds_h[w][256 + hl * 8] = pk;
    }
    // own h2 (fp32) -> LDS (all 64 lanes, cols [0,256))
    const float4 a = *(const float4*)&xc[(size_t)node * 512 + c0];
    *(float4*)&lds_f[w][c0] = a;
    {
        __half2 a01 = __floats2half2_rn(a.x, a.y), a23 = __floats2half2_rn(a.z, a.w);
        float2 pa;
        *(__half2*)&pa.x = a01; *(__half2*)&pa.y = a23;
        *(float2*)&lds_h[w][c0] = pa;
    }
    // wave-synchronous: same-wave DS ordering + compiler lgkmcnt waits suffice

    const int r = lane & 15;
    const int quad = lane >> 4;

    // ---- phase 2: scores (fp32), 4 classes concurrently, 16-lane reduce ----
    // rotation swizzle jj=(i+r)&7 on LDS + matching weight reads: 16-way -> 2-way (free)
    float av[32];
#pragma unroll
    for (int i = 0; i < 8; ++i) {
        const int jj = (i + r) & 7;
        *(float4*)&av[i * 4] = *(const float4*)&lds_f[w][r * 32 + jj * 4];
    }

    float s0, s1;
#pragma unroll
    for (int t = 0; t < 2; ++t) {
        const int c = t * 4 + quad;
        const float* wp = &Wp[c * 512 + r * 32];
        float p = 0.f;
#pragma unroll
        for (int i = 0; i < 8; ++i) {
            const int jj = (i + r) & 7;
            const float4 wv = *(const float4*)&wp[jj * 4];
            p = fmaf(av[i * 4 + 0], wv.x, p);
            p = fmaf(av[i * 4 + 1], wv.y, p);
            p = fmaf(av[i * 4 + 2], wv.z, p);
            p = fmaf(av[i * 4 + 3], wv.w, p);
        }
        p += __shfl_xor(p, 1); p += __shfl_xor(p, 2);
        p += __shfl_xor(p, 4); p += __shfl_xor(p, 8);
        if (t == 0) s0 = p; else s1 = p;
    }
    float best = -3.0e38f;
    int bidx = 0;
#pragma unroll
    for (int c = 0; c < 8; ++c) {  // class order: first-max tiebreak = argmax
        const float v = __shfl((c < 4) ? s0 : s1, (c & 3) * 16);
        if (v > best) { best = v; bidx = c; }
    }

    // ---- phase 3: expert dots (fp16 x fp16, fp32 accum via fdot2) ----
    // rotation swizzle jj=(i+r)&3: 8-way -> 2-way (free)
    float4 ah[4];
#pragma unroll
    for (int i = 0; i < 4; ++i) {
        const int jj = (i + r) & 3;
        ah[i] = *(const float4*)&lds_h[w][r * 32 + jj * 8];
    }

    const __half* web = We_h + (size_t)bidx * 40 * 512;
#pragma unroll
    for (int t = 0; t < 10; ++t) {
        const int c = t * 4 + quad;
        const __half* wr_ = web + c * 512 + r * 32;
        float p = 0.f;
#pragma unroll
        for (int i = 0; i < 4; ++i) {
            const int jj = (i + r) & 3;
            const float4 wv = *(const float4*)&wr_[jj * 8];
            p = dot2acc(ah[i].x, wv.x, p);
            p = dot2acc(ah[i].y, wv.y, p);
            p = dot2acc(ah[i].z, wv.z, p);
            p = dot2acc(ah[i].w, wv.w, p);
        }
        p += __shfl_xor(p, 1); p += __shfl_xor(p, 2);
        p += __shfl_xor(p, 4); p += __shfl_xor(p, 8);
        if (r == 0) out[(size_t)node * 40 + c] = p;
    }
}

extern "C" void kernel_launch(void* const* d_in, const int* in_sizes, int n_in,
                              void* d_out, int out_size, void* d_ws, size_t ws_size,
                              hipStream_t stream) {
    const float* x  = (const float*)d_in[0];
    const int*  edge = (const int*)d_in[1];
    const float* W1 = (const float*)d_in[2];
    const float* b1 = (const float*)d_in[3];
    const float* W2 = (const float*)d_in[4];
    const float* b2 = (const float*)d_in[5];
    const float* Wp = (const float*)d_in[6];
    const float* We = (const float*)d_in[7];

    const int n = in_sizes[0] / 512;   // 50000
    const int e = in_sizes[1] / 2;     // 1600000
    const int half = n / 2;            // 25000
    const int* src = edge;
    const int* dst = edge + e;

    // ---- workspace layout (peak ~163 MB; aliasing documented) ----
    char* ws = (char*)d_ws;
    ushort* A1h = (ushort*)ws;                             // [half,512] bf16 hi
    ushort* A2h = (ushort*)(ws + (size_t)half * 512 * 2);  // [half,512] bf16 lo
    float*  t   = (float*)ws;                              // [n,256] fp32 (aliases A, after GEMM1)
    char* p = ws + (size_t)n * 512 * 2;
    ushort* B1 = (ushort*)p; p += (size_t)n * 512 * 2;     // [n,512] h1 hi
    __half* h2h = (__half*)B1;                             // [n,256] fp16 (aliases B1, after GEMM2)
    ushort* B2 = (ushort*)p; p += (size_t)n * 512 * 2;     // [n,512] h1 lo
    ushort* W1hT = (ushort*)p; p += 512 * 512 * 2;
    ushort* W1lT = (ushort*)p; p += 512 * 512 * 2;
    ushort* W2hT = (ushort*)p; p += 256 * 512 * 2;
    ushort* W2lT = (ushort*)p; p += 256 * 512 * 2;
    __half* We_h = (__half*)p; p += 8 * 40 * 512 * 2;
    auto align16 = [](size_t v) { return (v + 15) & ~(size_t)15; };
    float* dinv = (float*)p;    p += align16((size_t)n * 4);
    int* counts = (int*)p;      p += align16((size_t)n * 4);
    int* offsets = (int*)p;     p += align16((size_t)(n + 1) * 4);
    int* cursor = (int*)p;      p += align16((size_t)n * 4);
    int* ssrc = (int*)p;        // [e]

    float* out = (float*)d_out;                 // [n,40]
    float* xc = (float*)d_out + (size_t)n * 40; // [n,512]

    // ---- CSR build ----
    hipMemsetAsync(counts, 0, (size_t)n * 4, stream);
    hist_kernel<<<(e + 255) / 256, 256, 0, stream>>>(dst, counts, e);
    scan_kernel<<<1, 1024, 0, stream>>>(counts, offsets, cursor, dinv, n, e);
    scatter_kernel<<<(e + 255) / 256, 256, 0, stream>>>(src, dst, cursor, ssrc, e);

    // ---- weight prep ----
    wsplit_kernel<<<(512 * 512 + 255) / 256, 256, 0, stream>>>(W1, W1hT, W1lT, 512, 9, 511);
    wsplit_kernel<<<(512 * 256 + 255) / 256, 256, 0, stream>>>(W2, W2hT, W2lT, 512, 8, 255);
    weconv_kernel<<<(8 * 40 * 512 + 255) / 256, 256, 0, stream>>>(We, We_h, 8 * 40 * 512);

    // ---- layer 1 (two M-halves so A-pair fits aliased workspace) ----
    const int waves_half = (half * 64 + 255) / 256;
    for (int h = 0; h < 2; ++h) {
        agg512_kernel<<<waves_half, 256, 0, stream>>>(x, ssrc, offsets, dinv,
                                                      A1h, A2h, h * half, half);
        dim3 g1(512 / 128, (half + 127) / 128);
        gemm_split_kernel<1><<<g1, 256, 0, stream>>>(
            A1h, A2h, W1hT, W1lT, b1,
            B1 + (size_t)h * half * 512, B2 + (size_t)h * half * 512, nullptr,
            half, 512, 512, 512);
    }

    // ---- layer 2 GEMM: t = h1 @ W2 (fp32 out, aliases A region) ----
    dim3 g2(256 / 128, (n + 127) / 128);
    gemm_split_kernel<0><<<g2, 256, 0, stream>>>(
        B1, B2, W2hT, W2lT, nullptr, nullptr, nullptr, t, n, 256, 512, 256);

    // ---- layer 2 aggregation -> xc[:,0:256] + fp16 copy ----
    const int waves_grid = (n * 64 + 255) / 256;
    agg256_kernel<<<waves_grid, 256, 0, stream>>>(t, ssrc, offsets, dinv, b2, xc, h2h, n);

    // ---- fused neighbor-mean + MoE head ----
    mean_expert_kernel<<<waves_grid, 256, 0, stream>>>(ssrc, offsets, Wp, We_h, h2h, xc, out, n);
}

// Round 6
// 1368.975 us; speedup vs baseline: 1.4158x; 1.0898x over previous
//
#include <hip/hip_runtime.h>
#include <hip/hip_bf16.h>
#include <hip/hip_fp16.h>
#include <cstdint>
#include <cstddef>

// ---------------------------------------------------------------------------
// ROGPL_79517024518975: 2-layer GCN + mean-aggr + prototype-routed MoE head.
// Round 6:
//  - t (= h1@W2) stored fp16 by GEMM2 epilogue; agg256 gathers fp16 rows
//    (512B) with 2-edges-per-wave packing -> halves layer-2 gather traffic.
//    Error class identical to the (passing) fp16 mean-gather path (~2^-11).
//  - agg512 unchanged (measured at ~6.6 TB/s random-row service ceiling).
//  - mean_expert unchanged from R5 (2-edge gather + rotation swizzle).
//  - GEMMs: split-bf16 MFMA 3-term.
// ---------------------------------------------------------------------------

using short8 = __attribute__((ext_vector_type(8))) short;
using f32x4  = __attribute__((ext_vector_type(4))) float;
typedef _Float16 half2_t __attribute__((ext_vector_type(2)));

#define GLB_AS __attribute__((address_space(1)))
#define LDS_AS __attribute__((address_space(3)))

#if defined(__has_builtin)
# if __has_builtin(__builtin_amdgcn_fdot2)
#  define HAVE_FDOT2 1
# endif
#endif

__device__ inline float dot2acc(float a, float b, float acc) {
#ifdef HAVE_FDOT2
    return __builtin_amdgcn_fdot2(__builtin_bit_cast(half2_t, a),
                                  __builtin_bit_cast(half2_t, b), acc, false);
#else
    const __half2 ha = __builtin_bit_cast(__half2, a);
    const __half2 hb = __builtin_bit_cast(__half2, b);
    const float2 fa = __half22float2(ha);
    const float2 fb = __half22float2(hb);
    return fmaf(fa.y, fb.y, fmaf(fa.x, fb.x, acc));
#endif
}

__device__ inline ushort f2bf_rne(float v) {
    uint32_t u = __builtin_bit_cast(uint32_t, v);
    uint32_t r = (u + 0x7FFFu + ((u >> 16) & 1u)) >> 16;
    return (ushort)r;
}
__device__ inline float bf2f(ushort b) {
    uint32_t u = ((uint32_t)b) << 16;
    return __builtin_bit_cast(float, u);
}
__device__ inline void split1(float v, ushort& hi, ushort& lo) {
    hi = f2bf_rne(v);
    lo = f2bf_rne(v - bf2f(hi));
}

// ---------------- CSR build ------------------------------------------------
__global__ void hist_kernel(const int* __restrict__ dst, int* __restrict__ counts, int e) {
    int i = blockIdx.x * blockDim.x + threadIdx.x;
    if (i < e) atomicAdd(&counts[dst[i]], 1);
}

__global__ __launch_bounds__(1024) void scan_kernel(const int* __restrict__ counts,
                                                    int* __restrict__ offsets,
                                                    int* __restrict__ cursor,
                                                    float* __restrict__ dinv,
                                                    int n, int e) {
    __shared__ int sdata[1024];
    const int t = threadIdx.x;
    const int chunk = (n + 1023) / 1024;
    const int beg = t * chunk;
    const int end = min(beg + chunk, n);
    int s = 0;
    for (int j = beg; j < end; ++j) s += counts[j];
    sdata[t] = s;
    __syncthreads();
    for (int off = 1; off < 1024; off <<= 1) {
        int v = (t >= off) ? sdata[t - off] : 0;
        __syncthreads();
        sdata[t] += v;
        __syncthreads();
    }
    int run = sdata[t] - s;
    for (int j = beg; j < end; ++j) {
        int c = counts[j];
        offsets[j] = run;
        cursor[j]  = run;
        dinv[j] = rsqrtf((float)c + 1.0f);  // deg includes self-loop
        run += c;
    }
    if (t == 0) offsets[n] = e;
}

__global__ void scatter_kernel(const int* __restrict__ src, const int* __restrict__ dst,
                               int* __restrict__ cursor, int* __restrict__ ssrc, int e) {
    int i = blockIdx.x * blockDim.x + threadIdx.x;
    if (i < e) {
        int d = dst[i];
        int pos = atomicAdd(&cursor[d], 1);
        ssrc[pos] = src[i];
    }
}

// ---------------- weight preparation --------------------------------------
__global__ void wsplit_kernel(const float* __restrict__ W, ushort* __restrict__ WhT,
                              ushort* __restrict__ WlT, int K, int nshift, int nmask) {
    int gid = blockIdx.x * blockDim.x + threadIdx.x;
    if (gid >= (K << nshift)) return;
    int k = gid >> nshift;
    int nn = gid & nmask;
    ushort hi, lo;
    split1(W[gid], hi, lo);
    WhT[(size_t)nn * K + k] = hi;
    WlT[(size_t)nn * K + k] = lo;
}

__global__ void weconv_kernel(const float* __restrict__ We, __half* __restrict__ We_h, int total) {
    int gid = blockIdx.x * blockDim.x + threadIdx.x;
    if (gid < total) We_h[gid] = __float2half(We[gid]);
}

// ---------------- wave-per-node aggregations -------------------------------
__global__ __launch_bounds__(256) void agg512_kernel(const float* __restrict__ x,
                                                     const int* __restrict__ ssrc,
                                                     const int* __restrict__ offsets,
                                                     const float* __restrict__ dinv,
                                                     ushort* __restrict__ A1,
                                                     ushort* __restrict__ A2,
                                                     int base, int cnt) {
    const int lane = threadIdx.x & 63;
    const int local = (blockIdx.x * blockDim.x + threadIdx.x) >> 6;
    if (local >= cnt) return;
    const int node = base + local;
    const int beg = offsets[node], end = offsets[node + 1];
    const float di = dinv[node];
    const int c0 = lane * 4;
    float4 acc0 = make_float4(0.f, 0.f, 0.f, 0.f);
    float4 acc1 = make_float4(0.f, 0.f, 0.f, 0.f);
    for (int b0 = beg; b0 < end; b0 += 64) {
        const int idx = b0 + lane;
        const int sl = (idx < end) ? ssrc[idx] : 0;
        const float wl = (idx < end) ? di * dinv[sl] : 0.f;
        const int m = min(64, end - b0);
#pragma unroll 8
        for (int k = 0; k < m; ++k) {
            const int s = __shfl(sl, k);
            const float w = __shfl(wl, k);
            const float* r = &x[(size_t)s * 512];
            const float4 v0 = *(const float4*)&r[c0];
            const float4 v1 = *(const float4*)&r[c0 + 256];
            acc0.x = fmaf(w, v0.x, acc0.x); acc0.y = fmaf(w, v0.y, acc0.y);
            acc0.z = fmaf(w, v0.z, acc0.z); acc0.w = fmaf(w, v0.w, acc0.w);
            acc1.x = fmaf(w, v1.x, acc1.x); acc1.y = fmaf(w, v1.y, acc1.y);
            acc1.z = fmaf(w, v1.z, acc1.z); acc1.w = fmaf(w, v1.w, acc1.w);
        }
    }
    {   // self-loop
        const float w = di * di;
        const float* r = &x[(size_t)node * 512];
        const float4 v0 = *(const float4*)&r[c0];
        const float4 v1 = *(const float4*)&r[c0 + 256];
        acc0.x = fmaf(w, v0.x, acc0.x); acc0.y = fmaf(w, v0.y, acc0.y);
        acc0.z = fmaf(w, v0.z, acc0.z); acc0.w = fmaf(w, v0.w, acc0.w);
        acc1.x = fmaf(w, v1.x, acc1.x); acc1.y = fmaf(w, v1.y, acc1.y);
        acc1.z = fmaf(w, v1.z, acc1.z); acc1.w = fmaf(w, v1.w, acc1.w);
    }
    ushort4 h0, l0, h1v, l1v;
    split1(acc0.x, h0.x, l0.x); split1(acc0.y, h0.y, l0.y);
    split1(acc0.z, h0.z, l0.z); split1(acc0.w, h0.w, l0.w);
    split1(acc1.x, h1v.x, l1v.x); split1(acc1.y, h1v.y, l1v.y);
    split1(acc1.z, h1v.z, l1v.z); split1(acc1.w, h1v.w, l1v.w);
    const size_t r = (size_t)local * 512;
    *(ushort4*)&A1[r + c0] = h0;       *(ushort4*)&A1[r + 256 + c0] = h1v;
    *(ushort4*)&A2[r + c0] = l0;       *(ushort4*)&A2[r + 256 + c0] = l1v;
}

// 256-col GCN-normalized aggregation of fp16 t + bias -> xc cols [0,256)
// (fp32) and h2h (fp16 copy). 2 edges per wave: half-wave h (32 lanes x 16B
// = 8 fp16 cols/lane) reads edge k=kp+h; combine partials via shfl.
__global__ __launch_bounds__(256) void agg256_kernel(const __half* __restrict__ th,
                                                     const int* __restrict__ ssrc,
                                                     const int* __restrict__ offsets,
                                                     const float* __restrict__ dinv,
                                                     const float* __restrict__ bias,
                                                     float* __restrict__ xc,
                                                     __half* __restrict__ h2h, int n) {
    const int lane = threadIdx.x & 63;
    const int node = (blockIdx.x * blockDim.x + threadIdx.x) >> 6;
    if (node >= n) return;
    const int beg = offsets[node], end = offsets[node + 1];
    const float di = dinv[node];
    const int half = lane >> 5;   // which edge of the pair
    const int hl = lane & 31;     // lane within half-wave; owns cols [hl*8, hl*8+8)

    float acc8[8] = {0.f, 0.f, 0.f, 0.f, 0.f, 0.f, 0.f, 0.f};
    for (int b0 = beg; b0 < end; b0 += 64) {
        const int idx = b0 + lane;
        const int sl = (idx < end) ? ssrc[idx] : 0;
        const float wl = (idx < end) ? di * dinv[sl] : 0.f;
        const int m = min(64, end - b0);
#pragma unroll 8
        for (int kp = 0; kp < m; kp += 2) {
            const int k = kp + half;          // k <= m; lanes >= m have wl=0
            const int s = __shfl(sl, k);      // 0 when padded -> row 0, w=0
            const float w = __shfl(wl, k);
            const float4 raw = *(const float4*)&th[(size_t)s * 256 + hl * 8];
            const float2 f0 = __half22float2(*(const __half2*)&raw.x);
            const float2 f1 = __half22float2(*(const __half2*)&raw.y);
            const float2 f2 = __half22float2(*(const __half2*)&raw.z);
            const float2 f3 = __half22float2(*(const __half2*)&raw.w);
            acc8[0] = fmaf(w, f0.x, acc8[0]); acc8[1] = fmaf(w, f0.y, acc8[1]);
            acc8[2] = fmaf(w, f1.x, acc8[2]); acc8[3] = fmaf(w, f1.y, acc8[3]);
            acc8[4] = fmaf(w, f2.x, acc8[4]); acc8[5] = fmaf(w, f2.y, acc8[5]);
            acc8[6] = fmaf(w, f3.x, acc8[6]); acc8[7] = fmaf(w, f3.y, acc8[7]);
        }
    }
    // combine the two half-wave partials into lanes 0-31
#pragma unroll
    for (int j = 0; j < 8; ++j) acc8[j] += __shfl(acc8[j], hl + 32);

    if (half == 0) {
        // self-loop (fp16 t, consistent quantization) + bias
        const float w = di * di;
        const float4 raw = *(const float4*)&th[(size_t)node * 256 + hl * 8];
        const float2 f0 = __half22float2(*(const __half2*)&raw.x);
        const float2 f1 = __half22float2(*(const __half2*)&raw.y);
        const float2 f2 = __half22float2(*(const __half2*)&raw.z);
        const float2 f3 = __half22float2(*(const __half2*)&raw.w);
        const float4 bv0 = *(const float4*)&bias[hl * 8];
        const float4 bv1 = *(const float4*)&bias[hl * 8 + 4];
        acc8[0] = fmaf(w, f0.x, acc8[0]) + bv0.x;
        acc8[1] = fmaf(w, f0.y, acc8[1]) + bv0.y;
        acc8[2] = fmaf(w, f1.x, acc8[2]) + bv0.z;
        acc8[3] = fmaf(w, f1.y, acc8[3]) + bv0.w;
        acc8[4] = fmaf(w, f2.x, acc8[4]) + bv1.x;
        acc8[5] = fmaf(w, f2.y, acc8[5]) + bv1.y;
        acc8[6] = fmaf(w, f3.x, acc8[6]) + bv1.z;
        acc8[7] = fmaf(w, f3.y, acc8[7]) + bv1.w;
        *(float4*)&xc[(size_t)node * 512 + hl * 8]     = make_float4(acc8[0], acc8[1], acc8[2], acc8[3]);
        *(float4*)&xc[(size_t)node * 512 + hl * 8 + 4] = make_float4(acc8[4], acc8[5], acc8[6], acc8[7]);
        __half2 q0 = __floats2half2_rn(acc8[0], acc8[1]), q1 = __floats2half2_rn(acc8[2], acc8[3]);
        __half2 q2 = __floats2half2_rn(acc8[4], acc8[5]), q3 = __floats2half2_rn(acc8[6], acc8[7]);
        float4 pk;
        *(__half2*)&pk.x = q0; *(__half2*)&pk.y = q1;
        *(__half2*)&pk.z = q2; *(__half2*)&pk.w = q3;
        *(float4*)&h2h[(size_t)node * 256 + hl * 8] = pk;
    }
}

// ---------------- split-bf16 MFMA GEMM (3-term) ----------------------------
// EPI 0: fp32 C.  EPI 1: relu(C+bias) -> bf16 hi/lo pair.  EPI 2: fp16 C.
template <int EPI>
__global__ __launch_bounds__(256) void gemm_split_kernel(
    const ushort* __restrict__ Ah, const ushort* __restrict__ Al,
    const ushort* __restrict__ WhT, const ushort* __restrict__ WlT,
    const float* __restrict__ bias,
    ushort* __restrict__ Ch, ushort* __restrict__ Cl,
    float* __restrict__ Cf, __half* __restrict__ Cf16,
    int M, int N, int K, int ldc) {
    __shared__ ushort smem[4 * 4096];  // Ah | Al | WhT | WlT tiles, each 128x32 bf16
    const int tid = threadIdx.x;
    const int lane = tid & 63;
    const int w = tid >> 6;
    const int wr = w >> 1, wc = w & 1;
    const int bm = blockIdx.y * 128;
    const int bn = blockIdx.x * 128;

    f32x4 acc[4][4];
#pragma unroll
    for (int i = 0; i < 4; ++i)
#pragma unroll
        for (int j = 0; j < 4; ++j) acc[i][j] = f32x4{0.f, 0.f, 0.f, 0.f};

    const ushort* sbase = (w == 0) ? Ah : (w == 1) ? Al : (w == 2) ? WhT : WlT;
    const int rowbase = (w < 2) ? bm : bn;
    const int rowmax = (w < 2) ? (M - 1) : (N - 1);

    for (int k0 = 0; k0 < K; k0 += 32) {
        __syncthreads();
#pragma unroll
        for (int i = 0; i < 8; ++i) {
            const int c = i * 64 + lane;
            int row = rowbase + (c >> 2);
            row = min(row, rowmax);
            const ushort* g = sbase + (size_t)row * K + k0 + (c & 3) * 8;
            __builtin_amdgcn_global_load_lds((const GLB_AS void*)g,
                                             (LDS_AS void*)(smem + w * 4096 + i * 512),
                                             16, 0, 0);
        }
        __syncthreads();

        const int koff = (lane >> 4) * 8;
        const int rsel = lane & 15;
        short8 a1[4], a2[4], b1[4], b2[4];
#pragma unroll
        for (int f = 0; f < 4; ++f) {
            const int ar = wr * 64 + f * 16 + rsel;
            a1[f] = *(const short8*)&smem[0 * 4096 + ar * 32 + koff];
            a2[f] = *(const short8*)&smem[1 * 4096 + ar * 32 + koff];
            const int bc = wc * 64 + f * 16 + rsel;
            b1[f] = *(const short8*)&smem[2 * 4096 + bc * 32 + koff];
            b2[f] = *(const short8*)&smem[3 * 4096 + bc * 32 + koff];
        }
        // 3-term: Ah*Bh + Ah*Bl + Al*Bh (Al*Bl ~1e-6 relative, dropped)
#pragma unroll
        for (int i = 0; i < 4; ++i)
#pragma unroll
            for (int j = 0; j < 4; ++j) {
                acc[i][j] = __builtin_amdgcn_mfma_f32_16x16x32_bf16(a1[i], b1[j], acc[i][j], 0, 0, 0);
                acc[i][j] = __builtin_amdgcn_mfma_f32_16x16x32_bf16(a1[i], b2[j], acc[i][j], 0, 0, 0);
                acc[i][j] = __builtin_amdgcn_mfma_f32_16x16x32_bf16(a2[i], b1[j], acc[i][j], 0, 0, 0);
            }
    }

    const int crow0 = wr * 64 + (lane >> 4) * 4;
    const int ccol0 = wc * 64 + (lane & 15);
#pragma unroll
    for (int f = 0; f < 4; ++f) {
#pragma unroll
        for (int g = 0; g < 4; ++g) {
            const int colg = bn + ccol0 + g * 16;
            float bv = 0.f;
            if constexpr (EPI == 1) bv = bias[colg];
#pragma unroll
            for (int j = 0; j < 4; ++j) {
                const int rowg = bm + crow0 + f * 16 + j;
                if (rowg >= M) continue;
                float v = acc[f][g][j];
                if constexpr (EPI == 1) {
                    v = fmaxf(v + bv, 0.f);
                    ushort hi, lo;
                    split1(v, hi, lo);
                    Ch[(size_t)rowg * ldc + colg] = hi;
                    Cl[(size_t)rowg * ldc + colg] = lo;
                } else if constexpr (EPI == 2) {
                    Cf16[(size_t)rowg * ldc + colg] = __float2half(v);
                } else {
                    Cf[(size_t)rowg * ldc + colg] = v;
                }
            }
        }
    }
}

// ---------------- fused mean-aggregation + MoE head ------------------------
__global__ __launch_bounds__(256) void mean_expert_kernel(const int* __restrict__ ssrc,
                                                          const int* __restrict__ offsets,
                                                          const float* __restrict__ Wp,
                                                          const __half* __restrict__ We_h,
                                                          const __half* __restrict__ h2h,
                                                          float* __restrict__ xc,
                                                          float* __restrict__ out, int n) {
    __shared__ float  lds_f[4][512];
    __shared__ __half lds_h[4][512];
    const int lane = threadIdx.x & 63;
    const int w = threadIdx.x >> 6;
    const int node = (blockIdx.x * blockDim.x + threadIdx.x) >> 6;
    if (node >= n) return;
    const int beg = offsets[node], end = offsets[node + 1];
    const int c0 = lane * 4;
    const int half = lane >> 5;
    const int hl = lane & 31;

    // ---- phase 1: neighbor mean of h2 (fp16 rows), 2 rows per wave-instr ----
    float acc8[8] = {0.f, 0.f, 0.f, 0.f, 0.f, 0.f, 0.f, 0.f};
    for (int b0 = beg; b0 < end; b0 += 64) {
        const int idx = b0 + lane;
        const int sl = (idx < end) ? ssrc[idx] : 0;
        const int m = min(64, end - b0);
#pragma unroll 8
        for (int kp = 0; kp < m; kp += 2) {
            const int k = kp + half;
            const int s = __shfl(sl, k);
            float4 raw = make_float4(0.f, 0.f, 0.f, 0.f);
            if (k < m) raw = *(const float4*)&h2h[(size_t)s * 256 + hl * 8];
            const float2 f0 = __half22float2(*(const __half2*)&raw.x);
            const float2 f1 = __half22float2(*(const __half2*)&raw.y);
            const float2 f2 = __half22float2(*(const __half2*)&raw.z);
            const float2 f3 = __half22float2(*(const __half2*)&raw.w);
            acc8[0] += f0.x; acc8[1] += f0.y; acc8[2] += f1.x; acc8[3] += f1.y;
            acc8[4] += f2.x; acc8[5] += f2.y; acc8[6] += f3.x; acc8[7] += f3.y;
        }
    }
#pragma unroll
    for (int j = 0; j < 8; ++j) acc8[j] += __shfl(acc8[j], hl + 32);

    const float inv = 1.f / fmaxf((float)(end - beg), 1.f);
    if (half == 0) {
        float4 b0v = make_float4(acc8[0] * inv, acc8[1] * inv, acc8[2] * inv, acc8[3] * inv);
        float4 b1v = make_float4(acc8[4] * inv, acc8[5] * inv, acc8[6] * inv, acc8[7] * inv);
        *(float4*)&xc[(size_t)node * 512 + 256 + hl * 8] = b0v;
        *(float4*)&xc[(size_t)node * 512 + 256 + hl * 8 + 4] = b1v;
        *(float4*)&lds_f[w][256 + hl * 8] = b0v;
        *(float4*)&lds_f[w][256 + hl * 8 + 4] = b1v;
        __half2 q0 = __floats2half2_rn(b0v.x, b0v.y), q1 = __floats2half2_rn(b0v.z, b0v.w);
        __half2 q2 = __floats2half2_rn(b1v.x, b1v.y), q3 = __floats2half2_rn(b1v.z, b1v.w);
        float4 pk;
        *(__half2*)&pk.x = q0; *(__half2*)&pk.y = q1;
        *(__half2*)&pk.z = q2; *(__half2*)&pk.w = q3;
        *(float4*)&lds_h[w][256 + hl * 8] = pk;
    }
    const float4 a = *(const float4*)&xc[(size_t)node * 512 + c0];
    *(float4*)&lds_f[w][c0] = a;
    {
        __half2 a01 = __floats2half2_rn(a.x, a.y), a23 = __floats2half2_rn(a.z, a.w);
        float2 pa;
        *(__half2*)&pa.x = a01; *(__half2*)&pa.y = a23;
        *(float2*)&lds_h[w][c0] = pa;
    }
    // wave-synchronous: same-wave DS ordering + compiler lgkmcnt waits suffice

    const int r = lane & 15;
    const int quad = lane >> 4;

    // ---- phase 2: scores (fp32), 4 classes concurrently, 16-lane reduce ----
    float av[32];
#pragma unroll
    for (int i = 0; i < 8; ++i) {
        const int jj = (i + r) & 7;
        *(float4*)&av[i * 4] = *(const float4*)&lds_f[w][r * 32 + jj * 4];
    }

    float s0, s1;
#pragma unroll
    for (int t = 0; t < 2; ++t) {
        const int c = t * 4 + quad;
        const float* wp = &Wp[c * 512 + r * 32];
        float p = 0.f;
#pragma unroll
        for (int i = 0; i < 8; ++i) {
            const int jj = (i + r) & 7;
            const float4 wv = *(const float4*)&wp[jj * 4];
            p = fmaf(av[i * 4 + 0], wv.x, p);
            p = fmaf(av[i * 4 + 1], wv.y, p);
            p = fmaf(av[i * 4 + 2], wv.z, p);
            p = fmaf(av[i * 4 + 3], wv.w, p);
        }
        p += __shfl_xor(p, 1); p += __shfl_xor(p, 2);
        p += __shfl_xor(p, 4); p += __shfl_xor(p, 8);
        if (t == 0) s0 = p; else s1 = p;
    }
    float best = -3.0e38f;
    int bidx = 0;
#pragma unroll
    for (int c = 0; c < 8; ++c) {
        const float v = __shfl((c < 4) ? s0 : s1, (c & 3) * 16);
        if (v > best) { best = v; bidx = c; }
    }

    // ---- phase 3: expert dots (fp16 x fp16, fp32 accum via fdot2) ----
    float4 ah[4];
#pragma unroll
    for (int i = 0; i < 4; ++i) {
        const int jj = (i + r) & 3;
        ah[i] = *(const float4*)&lds_h[w][r * 32 + jj * 8];
    }

    const __half* web = We_h + (size_t)bidx * 40 * 512;
#pragma unroll
    for (int t = 0; t < 10; ++t) {
        const int c = t * 4 + quad;
        const __half* wr_ = web + c * 512 + r * 32;
        float p = 0.f;
#pragma unroll
        for (int i = 0; i < 4; ++i) {
            const int jj = (i + r) & 3;
            const float4 wv = *(const float4*)&wr_[jj * 8];
            p = dot2acc(ah[i].x, wv.x, p);
            p = dot2acc(ah[i].y, wv.y, p);
            p = dot2acc(ah[i].z, wv.z, p);
            p = dot2acc(ah[i].w, wv.w, p);
        }
        p += __shfl_xor(p, 1); p += __shfl_xor(p, 2);
        p += __shfl_xor(p, 4); p += __shfl_xor(p, 8);
        if (r == 0) out[(size_t)node * 40 + c] = p;
    }
}

extern "C" void kernel_launch(void* const* d_in, const int* in_sizes, int n_in,
                              void* d_out, int out_size, void* d_ws, size_t ws_size,
                              hipStream_t stream) {
    const float* x  = (const float*)d_in[0];
    const int*  edge = (const int*)d_in[1];
    const float* W1 = (const float*)d_in[2];
    const float* b1 = (const float*)d_in[3];
    const float* W2 = (const float*)d_in[4];
    const float* b2 = (const float*)d_in[5];
    const float* Wp = (const float*)d_in[6];
    const float* We = (const float*)d_in[7];

    const int n = in_sizes[0] / 512;   // 50000
    const int e = in_sizes[1] / 2;     // 1600000
    const int half = n / 2;            // 25000
    const int* src = edge;
    const int* dst = edge + e;

    // ---- workspace layout (peak ~163 MB; aliasing documented) ----
    char* ws = (char*)d_ws;
    ushort* A1h = (ushort*)ws;                             // [half,512] bf16 hi
    ushort* A2h = (ushort*)(ws + (size_t)half * 512 * 2);  // [half,512] bf16 lo
    __half* t16 = (__half*)ws;                             // [n,256] fp16 (aliases A, after GEMM1)
    char* p = ws + (size_t)n * 512 * 2;
    ushort* B1 = (ushort*)p; p += (size_t)n * 512 * 2;     // [n,512] h1 hi
    __half* h2h = (__half*)B1;                             // [n,256] fp16 (aliases B1, after GEMM2)
    ushort* B2 = (ushort*)p; p += (size_t)n * 512 * 2;     // [n,512] h1 lo
    ushort* W1hT = (ushort*)p; p += 512 * 512 * 2;
    ushort* W1lT = (ushort*)p; p += 512 * 512 * 2;
    ushort* W2hT = (ushort*)p; p += 256 * 512 * 2;
    ushort* W2lT = (ushort*)p; p += 256 * 512 * 2;
    __half* We_h = (__half*)p; p += 8 * 40 * 512 * 2;
    auto align16 = [](size_t v) { return (v + 15) & ~(size_t)15; };
    float* dinv = (float*)p;    p += align16((size_t)n * 4);
    int* counts = (int*)p;      p += align16((size_t)n * 4);
    int* offsets = (int*)p;     p += align16((size_t)(n + 1) * 4);
    int* cursor = (int*)p;      p += align16((size_t)n * 4);
    int* ssrc = (int*)p;        // [e]

    float* out = (float*)d_out;                 // [n,40]
    float* xc = (float*)d_out + (size_t)n * 40; // [n,512]

    // ---- CSR build ----
    hipMemsetAsync(counts, 0, (size_t)n * 4, stream);
    hist_kernel<<<(e + 255) / 256, 256, 0, stream>>>(dst, counts, e);
    scan_kernel<<<1, 1024, 0, stream>>>(counts, offsets, cursor, dinv, n, e);
    scatter_kernel<<<(e + 255) / 256, 256, 0, stream>>>(src, dst, cursor, ssrc, e);

    // ---- weight prep ----
    wsplit_kernel<<<(512 * 512 + 255) / 256, 256, 0, stream>>>(W1, W1hT, W1lT, 512, 9, 511);
    wsplit_kernel<<<(512 * 256 + 255) / 256, 256, 0, stream>>>(W2, W2hT, W2lT, 512, 8, 255);
    weconv_kernel<<<(8 * 40 * 512 + 255) / 256, 256, 0, stream>>>(We, We_h, 8 * 40 * 512);

    // ---- layer 1 (two M-halves so A-pair fits aliased workspace) ----
    const int waves_half = (half * 64 + 255) / 256;
    for (int h = 0; h < 2; ++h) {
        agg512_kernel<<<waves_half, 256, 0, stream>>>(x, ssrc, offsets, dinv,
                                                      A1h, A2h, h * half, half);
        dim3 g1(512 / 128, (half + 127) / 128);
        gemm_split_kernel<1><<<g1, 256, 0, stream>>>(
            A1h, A2h, W1hT, W1lT, b1,
            B1 + (size_t)h * half * 512, B2 + (size_t)h * half * 512, nullptr, nullptr,
            half, 512, 512, 512);
    }

    // ---- layer 2 GEMM: t16 = fp16(h1 @ W2) (aliases A region) ----
    dim3 g2(256 / 128, (n + 127) / 128);
    gemm_split_kernel<2><<<g2, 256, 0, stream>>>(
        B1, B2, W2hT, W2lT, nullptr, nullptr, nullptr, nullptr, t16, n, 256, 512, 256);

    // ---- layer 2 aggregation (fp16 gather) -> xc[:,0:256] + fp16 copy ----
    const int waves_grid = (n * 64 + 255) / 256;
    agg256_kernel<<<waves_grid, 256, 0, stream>>>(t16, ssrc, offsets, dinv, b2, xc, h2h, n);

    // ---- fused neighbor-mean + MoE head ----
    mean_expert_kernel<<<waves_grid, 256, 0, stream>>>(ssrc, offsets, Wp, We_h, h2h, xc, out, n);
}

// Round 7
// 1129.742 us; speedup vs baseline: 1.7156x; 1.2118x over previous
//
#include <hip/hip_runtime.h>
#include <hip/hip_bf16.h>
#include <hip/hip_fp16.h>
#include <cstdint>
#include <cstddef>

// ---------------------------------------------------------------------------
// ROGPL_79517024518975: 2-layer GCN + mean-aggr + prototype-routed MoE head.
// Round 7:
//  - x converted to fp16 once; agg512 gathers 1KB fp16 rows (was 2KB fp32):
//    halves the dominant gather traffic. Error 2^-11, attenuated by W1/W2.
//  - h1 stored as SINGLE fp16 (frees 51.2MB, pays for x16; err ~7e-5 on t).
//  - GEMM2: 2-term f16 MFMA (A fp16 single x W2 fp16 hi/lo pair).
//  - GEMM1: bf16 3-term split MFMA (unchanged), epilogue -> fp16 h1.
//  - agg256/mean_expert unchanged from R6.
// ---------------------------------------------------------------------------

using short8 = __attribute__((ext_vector_type(8))) short;
using half8  = __attribute__((ext_vector_type(8))) _Float16;
using f32x4  = __attribute__((ext_vector_type(4))) float;
typedef _Float16 half2_t __attribute__((ext_vector_type(2)));

#define GLB_AS __attribute__((address_space(1)))
#define LDS_AS __attribute__((address_space(3)))

#if defined(__has_builtin)
# if __has_builtin(__builtin_amdgcn_fdot2)
#  define HAVE_FDOT2 1
# endif
#endif

__device__ inline float dot2acc(float a, float b, float acc) {
#ifdef HAVE_FDOT2
    return __builtin_amdgcn_fdot2(__builtin_bit_cast(half2_t, a),
                                  __builtin_bit_cast(half2_t, b), acc, false);
#else
    const __half2 ha = __builtin_bit_cast(__half2, a);
    const __half2 hb = __builtin_bit_cast(__half2, b);
    const float2 fa = __half22float2(ha);
    const float2 fb = __half22float2(hb);
    return fmaf(fa.y, fb.y, fmaf(fa.x, fb.x, acc));
#endif
}

__device__ inline ushort f2bf_rne(float v) {
    uint32_t u = __builtin_bit_cast(uint32_t, v);
    uint32_t r = (u + 0x7FFFu + ((u >> 16) & 1u)) >> 16;
    return (ushort)r;
}
__device__ inline float bf2f(ushort b) {
    uint32_t u = ((uint32_t)b) << 16;
    return __builtin_bit_cast(float, u);
}
__device__ inline void split1(float v, ushort& hi, ushort& lo) {
    hi = f2bf_rne(v);
    lo = f2bf_rne(v - bf2f(hi));
}

// ---------------- CSR build ------------------------------------------------
__global__ void hist_kernel(const int* __restrict__ dst, int* __restrict__ counts, int e) {
    int i = blockIdx.x * blockDim.x + threadIdx.x;
    if (i < e) atomicAdd(&counts[dst[i]], 1);
}

__global__ __launch_bounds__(1024) void scan_kernel(const int* __restrict__ counts,
                                                    int* __restrict__ offsets,
                                                    int* __restrict__ cursor,
                                                    float* __restrict__ dinv,
                                                    int n, int e) {
    __shared__ int sdata[1024];
    const int t = threadIdx.x;
    const int chunk = (n + 1023) / 1024;
    const int beg = t * chunk;
    const int end = min(beg + chunk, n);
    int s = 0;
    for (int j = beg; j < end; ++j) s += counts[j];
    sdata[t] = s;
    __syncthreads();
    for (int off = 1; off < 1024; off <<= 1) {
        int v = (t >= off) ? sdata[t - off] : 0;
        __syncthreads();
        sdata[t] += v;
        __syncthreads();
    }
    int run = sdata[t] - s;
    for (int j = beg; j < end; ++j) {
        int c = counts[j];
        offsets[j] = run;
        cursor[j]  = run;
        dinv[j] = rsqrtf((float)c + 1.0f);  // deg includes self-loop
        run += c;
    }
    if (t == 0) offsets[n] = e;
}

__global__ void scatter_kernel(const int* __restrict__ src, const int* __restrict__ dst,
                               int* __restrict__ cursor, int* __restrict__ ssrc, int e) {
    int i = blockIdx.x * blockDim.x + threadIdx.x;
    if (i < e) {
        int d = dst[i];
        int pos = atomicAdd(&cursor[d], 1);
        ssrc[pos] = src[i];
    }
}

// ---------------- conversions / weight prep --------------------------------
// x fp32 -> fp16, 8 elems/thread
__global__ void xconv_kernel(const float* __restrict__ x, __half* __restrict__ x16, int total8) {
    int i = blockIdx.x * blockDim.x + threadIdx.x;
    if (i >= total8) return;
    const float4 v0 = ((const float4*)x)[(size_t)i * 2];
    const float4 v1 = ((const float4*)x)[(size_t)i * 2 + 1];
    __half2 q0 = __floats2half2_rn(v0.x, v0.y), q1 = __floats2half2_rn(v0.z, v0.w);
    __half2 q2 = __floats2half2_rn(v1.x, v1.y), q3 = __floats2half2_rn(v1.z, v1.w);
    float4 pk;
    *(__half2*)&pk.x = q0; *(__half2*)&pk.y = q1;
    *(__half2*)&pk.z = q2; *(__half2*)&pk.w = q3;
    ((float4*)x16)[i] = pk;
}

// W [K][N] fp32 -> WhT/WlT [N][K] bf16 hi/lo (GEMM1 B operand)
__global__ void wsplit_kernel(const float* __restrict__ W, ushort* __restrict__ WhT,
                              ushort* __restrict__ WlT, int K, int nshift, int nmask) {
    int gid = blockIdx.x * blockDim.x + threadIdx.x;
    if (gid >= (K << nshift)) return;
    int k = gid >> nshift;
    int nn = gid & nmask;
    ushort hi, lo;
    split1(W[gid], hi, lo);
    WhT[(size_t)nn * K + k] = hi;
    WlT[(size_t)nn * K + k] = lo;
}

// W [K][N] fp32 -> WhT/WlT [N][K] fp16 hi/lo (GEMM2 B operand)
__global__ void wsplit16_kernel(const float* __restrict__ W, __half* __restrict__ WhT,
                                __half* __restrict__ WlT, int K, int nshift, int nmask) {
    int gid = blockIdx.x * blockDim.x + threadIdx.x;
    if (gid >= (K << nshift)) return;
    int k = gid >> nshift;
    int nn = gid & nmask;
    float v = W[gid];
    __half hi = __float2half(v);
    __half lo = __float2half(v - __half2float(hi));
    WhT[(size_t)nn * K + k] = hi;
    WlT[(size_t)nn * K + k] = lo;
}

__global__ void weconv_kernel(const float* __restrict__ We, __half* __restrict__ We_h, int total) {
    int gid = blockIdx.x * blockDim.x + threadIdx.x;
    if (gid < total) We_h[gid] = __float2half(We[gid]);
}

// ---------------- wave-per-node aggregations -------------------------------
// 512-col GCN-normalized aggregation of fp16 x rows (1KB); emits bf16 hi/lo
// pair (GEMM1 A operand). Each lane owns 8 contiguous cols.
__global__ __launch_bounds__(256) void agg512_kernel(const __half* __restrict__ x16,
                                                     const int* __restrict__ ssrc,
                                                     const int* __restrict__ offsets,
                                                     const float* __restrict__ dinv,
                                                     ushort* __restrict__ A1,
                                                     ushort* __restrict__ A2,
                                                     int base, int cnt) {
    const int lane = threadIdx.x & 63;
    const int local = (blockIdx.x * blockDim.x + threadIdx.x) >> 6;
    if (local >= cnt) return;
    const int node = base + local;
    const int beg = offsets[node], end = offsets[node + 1];
    const float di = dinv[node];
    const int c0 = lane * 8;  // 8 fp16 cols per lane = 16B
    float acc[8] = {0.f, 0.f, 0.f, 0.f, 0.f, 0.f, 0.f, 0.f};
    for (int b0 = beg; b0 < end; b0 += 64) {
        const int idx = b0 + lane;
        const int sl = (idx < end) ? ssrc[idx] : 0;
        const float wl = (idx < end) ? di * dinv[sl] : 0.f;
        const int m = min(64, end - b0);
#pragma unroll 8
        for (int k = 0; k < m; ++k) {
            const int s = __shfl(sl, k);
            const float w = __shfl(wl, k);
            const float4 raw = *(const float4*)&x16[(size_t)s * 512 + c0];
            const float2 f0 = __half22float2(*(const __half2*)&raw.x);
            const float2 f1 = __half22float2(*(const __half2*)&raw.y);
            const float2 f2 = __half22float2(*(const __half2*)&raw.z);
            const float2 f3 = __half22float2(*(const __half2*)&raw.w);
            acc[0] = fmaf(w, f0.x, acc[0]); acc[1] = fmaf(w, f0.y, acc[1]);
            acc[2] = fmaf(w, f1.x, acc[2]); acc[3] = fmaf(w, f1.y, acc[3]);
            acc[4] = fmaf(w, f2.x, acc[4]); acc[5] = fmaf(w, f2.y, acc[5]);
            acc[6] = fmaf(w, f3.x, acc[6]); acc[7] = fmaf(w, f3.y, acc[7]);
        }
    }
    {   // self-loop (fp16 x, consistent quantization)
        const float w = di * di;
        const float4 raw = *(const float4*)&x16[(size_t)node * 512 + c0];
        const float2 f0 = __half22float2(*(const __half2*)&raw.x);
        const float2 f1 = __half22float2(*(const __half2*)&raw.y);
        const float2 f2 = __half22float2(*(const __half2*)&raw.z);
        const float2 f3 = __half22float2(*(const __half2*)&raw.w);
        acc[0] = fmaf(w, f0.x, acc[0]); acc[1] = fmaf(w, f0.y, acc[1]);
        acc[2] = fmaf(w, f1.x, acc[2]); acc[3] = fmaf(w, f1.y, acc[3]);
        acc[4] = fmaf(w, f2.x, acc[4]); acc[5] = fmaf(w, f2.y, acc[5]);
        acc[6] = fmaf(w, f3.x, acc[6]); acc[7] = fmaf(w, f3.y, acc[7]);
    }
    short8 hi8, lo8;
#pragma unroll
    for (int j = 0; j < 8; ++j) {
        ushort hi, lo;
        split1(acc[j], hi, lo);
        hi8[j] = (short)hi;
        lo8[j] = (short)lo;
    }
    const size_t r = (size_t)local * 512 + c0;
    *(short8*)&A1[r] = hi8;
    *(short8*)&A2[r] = lo8;
}

// 256-col GCN-normalized aggregation of fp16 t + bias -> xc cols [0,256)
// (fp32) and h2h (fp16 copy). 2 edges per wave.
__global__ __launch_bounds__(256) void agg256_kernel(const __half* __restrict__ th,
                                                     const int* __restrict__ ssrc,
                                                     const int* __restrict__ offsets,
                                                     const float* __restrict__ dinv,
                                                     const float* __restrict__ bias,
                                                     float* __restrict__ xc,
                                                     __half* __restrict__ h2h, int n) {
    const int lane = threadIdx.x & 63;
    const int node = (blockIdx.x * blockDim.x + threadIdx.x) >> 6;
    if (node >= n) return;
    const int beg = offsets[node], end = offsets[node + 1];
    const float di = dinv[node];
    const int half = lane >> 5;
    const int hl = lane & 31;

    float acc8[8] = {0.f, 0.f, 0.f, 0.f, 0.f, 0.f, 0.f, 0.f};
    for (int b0 = beg; b0 < end; b0 += 64) {
        const int idx = b0 + lane;
        const int sl = (idx < end) ? ssrc[idx] : 0;
        const float wl = (idx < end) ? di * dinv[sl] : 0.f;
        const int m = min(64, end - b0);
#pragma unroll 8
        for (int kp = 0; kp < m; kp += 2) {
            const int k = kp + half;          // k <= m; lanes >= m have wl=0
            const int s = __shfl(sl, k);
            const float w = __shfl(wl, k);
            const float4 raw = *(const float4*)&th[(size_t)s * 256 + hl * 8];
            const float2 f0 = __half22float2(*(const __half2*)&raw.x);
            const float2 f1 = __half22float2(*(const __half2*)&raw.y);
            const float2 f2 = __half22float2(*(const __half2*)&raw.z);
            const float2 f3 = __half22float2(*(const __half2*)&raw.w);
            acc8[0] = fmaf(w, f0.x, acc8[0]); acc8[1] = fmaf(w, f0.y, acc8[1]);
            acc8[2] = fmaf(w, f1.x, acc8[2]); acc8[3] = fmaf(w, f1.y, acc8[3]);
            acc8[4] = fmaf(w, f2.x, acc8[4]); acc8[5] = fmaf(w, f2.y, acc8[5]);
            acc8[6] = fmaf(w, f3.x, acc8[6]); acc8[7] = fmaf(w, f3.y, acc8[7]);
        }
    }
#pragma unroll
    for (int j = 0; j < 8; ++j) acc8[j] += __shfl(acc8[j], hl + 32);

    if (half == 0) {
        const float w = di * di;
        const float4 raw = *(const float4*)&th[(size_t)node * 256 + hl * 8];
        const float2 f0 = __half22float2(*(const __half2*)&raw.x);
        const float2 f1 = __half22float2(*(const __half2*)&raw.y);
        const float2 f2 = __half22float2(*(const __half2*)&raw.z);
        const float2 f3 = __half22float2(*(const __half2*)&raw.w);
        const float4 bv0 = *(const float4*)&bias[hl * 8];
        const float4 bv1 = *(const float4*)&bias[hl * 8 + 4];
        acc8[0] = fmaf(w, f0.x, acc8[0]) + bv0.x;
        acc8[1] = fmaf(w, f0.y, acc8[1]) + bv0.y;
        acc8[2] = fmaf(w, f1.x, acc8[2]) + bv0.z;
        acc8[3] = fmaf(w, f1.y, acc8[3]) + bv0.w;
        acc8[4] = fmaf(w, f2.x, acc8[4]) + bv1.x;
        acc8[5] = fmaf(w, f2.y, acc8[5]) + bv1.y;
        acc8[6] = fmaf(w, f3.x, acc8[6]) + bv1.z;
        acc8[7] = fmaf(w, f3.y, acc8[7]) + bv1.w;
        *(float4*)&xc[(size_t)node * 512 + hl * 8]     = make_float4(acc8[0], acc8[1], acc8[2], acc8[3]);
        *(float4*)&xc[(size_t)node * 512 + hl * 8 + 4] = make_float4(acc8[4], acc8[5], acc8[6], acc8[7]);
        __half2 q0 = __floats2half2_rn(acc8[0], acc8[1]), q1 = __floats2half2_rn(acc8[2], acc8[3]);
        __half2 q2 = __floats2half2_rn(acc8[4], acc8[5]), q3 = __floats2half2_rn(acc8[6], acc8[7]);
        float4 pk;
        *(__half2*)&pk.x = q0; *(__half2*)&pk.y = q1;
        *(__half2*)&pk.z = q2; *(__half2*)&pk.w = q3;
        *(float4*)&h2h[(size_t)node * 256 + hl * 8] = pk;
    }
}

// ---------------- GEMM1: bf16 3-term split MFMA, epilogue relu+bias -> fp16 -
__global__ __launch_bounds__(256) void gemm1_kernel(
    const ushort* __restrict__ Ah, const ushort* __restrict__ Al,
    const ushort* __restrict__ WhT, const ushort* __restrict__ WlT,
    const float* __restrict__ bias,
    __half* __restrict__ C,        // [M,512] fp16 h1
    int M, int N, int K) {
    __shared__ ushort smem[4 * 4096];  // Ah | Al | WhT | WlT tiles, each 128x32
    const int tid = threadIdx.x;
    const int lane = tid & 63;
    const int w = tid >> 6;
    const int wr = w >> 1, wc = w & 1;
    const int bm = blockIdx.y * 128;
    const int bn = blockIdx.x * 128;

    f32x4 acc[4][4];
#pragma unroll
    for (int i = 0; i < 4; ++i)
#pragma unroll
        for (int j = 0; j < 4; ++j) acc[i][j] = f32x4{0.f, 0.f, 0.f, 0.f};

    const ushort* sbase = (w == 0) ? Ah : (w == 1) ? Al : (w == 2) ? WhT : WlT;
    const int rowbase = (w < 2) ? bm : bn;
    const int rowmax = (w < 2) ? (M - 1) : (N - 1);

    for (int k0 = 0; k0 < K; k0 += 32) {
        __syncthreads();
#pragma unroll
        for (int i = 0; i < 8; ++i) {
            const int c = i * 64 + lane;
            int row = rowbase + (c >> 2);
            row = min(row, rowmax);
            const ushort* g = sbase + (size_t)row * K + k0 + (c & 3) * 8;
            __builtin_amdgcn_global_load_lds((const GLB_AS void*)g,
                                             (LDS_AS void*)(smem + w * 4096 + i * 512),
                                             16, 0, 0);
        }
        __syncthreads();

        const int koff = (lane >> 4) * 8;
        const int rsel = lane & 15;
        short8 a1[4], a2[4], b1[4], b2[4];
#pragma unroll
        for (int f = 0; f < 4; ++f) {
            const int ar = wr * 64 + f * 16 + rsel;
            a1[f] = *(const short8*)&smem[0 * 4096 + ar * 32 + koff];
            a2[f] = *(const short8*)&smem[1 * 4096 + ar * 32 + koff];
            const int bc = wc * 64 + f * 16 + rsel;
            b1[f] = *(const short8*)&smem[2 * 4096 + bc * 32 + koff];
            b2[f] = *(const short8*)&smem[3 * 4096 + bc * 32 + koff];
        }
#pragma unroll
        for (int i = 0; i < 4; ++i)
#pragma unroll
            for (int j = 0; j < 4; ++j) {
                acc[i][j] = __builtin_amdgcn_mfma_f32_16x16x32_bf16(a1[i], b1[j], acc[i][j], 0, 0, 0);
                acc[i][j] = __builtin_amdgcn_mfma_f32_16x16x32_bf16(a1[i], b2[j], acc[i][j], 0, 0, 0);
                acc[i][j] = __builtin_amdgcn_mfma_f32_16x16x32_bf16(a2[i], b1[j], acc[i][j], 0, 0, 0);
            }
    }

    const int crow0 = wr * 64 + (lane >> 4) * 4;
    const int ccol0 = wc * 64 + (lane & 15);
#pragma unroll
    for (int f = 0; f < 4; ++f) {
#pragma unroll
        for (int g = 0; g < 4; ++g) {
            const int colg = bn + ccol0 + g * 16;
            const float bv = bias[colg];
#pragma unroll
            for (int j = 0; j < 4; ++j) {
                const int rowg = bm + crow0 + f * 16 + j;
                if (rowg >= M) continue;
                const float v = fmaxf(acc[f][g][j] + bv, 0.f);
                C[(size_t)rowg * 512 + colg] = __float2half(v);
            }
        }
    }
}

// ---------------- GEMM2: f16 2-term MFMA (A fp16 single, W fp16 pair) ------
__global__ __launch_bounds__(256) void gemm2_kernel(
    const __half* __restrict__ A,    // [M,512] fp16 h1
    const __half* __restrict__ WhT,  // [256,512] fp16
    const __half* __restrict__ WlT,
    __half* __restrict__ C,          // [M,256] fp16 t
    int M) {
    constexpr int K = 512, N = 256;
    __shared__ ushort smem[3 * 4096];  // A | WhT | WlT tiles, each 128x32 f16
    const int tid = threadIdx.x;
    const int lane = tid & 63;
    const int w = tid >> 6;
    const int wr = w >> 1, wc = w & 1;
    const int bm = blockIdx.y * 128;
    const int bn = blockIdx.x * 128;

    f32x4 acc[4][4];
#pragma unroll
    for (int i = 0; i < 4; ++i)
#pragma unroll
        for (int j = 0; j < 4; ++j) acc[i][j] = f32x4{0.f, 0.f, 0.f, 0.f};

    // staging roles: wave0 -> A, wave2 -> WhT, wave3 -> WlT, wave1 idle
    const ushort* sbase = (w == 0) ? (const ushort*)A
                        : (w == 3) ? (const ushort*)WlT : (const ushort*)WhT;
    const int rowbase = (w == 0) ? bm : bn;
    const int rowmax = (w == 0) ? (M - 1) : (N - 1);
    const int sslot = (w == 0) ? 0 : (w - 1);  // 0 / 1 / 2

    for (int k0 = 0; k0 < K; k0 += 32) {
        __syncthreads();
        if (w != 1) {
#pragma unroll
            for (int i = 0; i < 8; ++i) {
                const int c = i * 64 + lane;
                int row = rowbase + (c >> 2);
                row = min(row, rowmax);
                const ushort* g = sbase + (size_t)row * K + k0 + (c & 3) * 8;
                __builtin_amdgcn_global_load_lds((const GLB_AS void*)g,
                                                 (LDS_AS void*)(smem + sslot * 4096 + i * 512),
                                                 16, 0, 0);
            }
        }
        __syncthreads();

        const int koff = (lane >> 4) * 8;
        const int rsel = lane & 15;
        half8 a[4], b1[4], b2[4];
#pragma unroll
        for (int f = 0; f < 4; ++f) {
            const int ar = wr * 64 + f * 16 + rsel;
            a[f]  = __builtin_bit_cast(half8, *(const short8*)&smem[0 * 4096 + ar * 32 + koff]);
            const int bc = wc * 64 + f * 16 + rsel;
            b1[f] = __builtin_bit_cast(half8, *(const short8*)&smem[1 * 4096 + bc * 32 + koff]);
            b2[f] = __builtin_bit_cast(half8, *(const short8*)&smem[2 * 4096 + bc * 32 + koff]);
        }
#pragma unroll
        for (int i = 0; i < 4; ++i)
#pragma unroll
            for (int j = 0; j < 4; ++j) {
                acc[i][j] = __builtin_amdgcn_mfma_f32_16x16x32_f16(a[i], b1[j], acc[i][j], 0, 0, 0);
                acc[i][j] = __builtin_amdgcn_mfma_f32_16x16x32_f16(a[i], b2[j], acc[i][j], 0, 0, 0);
            }
    }

    const int crow0 = wr * 64 + (lane >> 4) * 4;
    const int ccol0 = wc * 64 + (lane & 15);
#pragma unroll
    for (int f = 0; f < 4; ++f) {
#pragma unroll
        for (int g = 0; g < 4; ++g) {
            const int colg = bn + ccol0 + g * 16;
#pragma unroll
            for (int j = 0; j < 4; ++j) {
                const int rowg = bm + crow0 + f * 16 + j;
                if (rowg >= M) continue;
                C[(size_t)rowg * 256 + colg] = __float2half(acc[f][g][j]);
            }
        }
    }
}

// ---------------- fused mean-aggregation + MoE head ------------------------
__global__ __launch_bounds__(256) void mean_expert_kernel(const int* __restrict__ ssrc,
                                                          const int* __restrict__ offsets,
                                                          const float* __restrict__ Wp,
                                                          const __half* __restrict__ We_h,
                                                          const __half* __restrict__ h2h,
                                                          float* __restrict__ xc,
                                                          float* __restrict__ out, int n) {
    __shared__ float  lds_f[4][512];
    __shared__ __half lds_h[4][512];
    const int lane = threadIdx.x & 63;
    const int w = threadIdx.x >> 6;
    const int node = (blockIdx.x * blockDim.x + threadIdx.x) >> 6;
    if (node >= n) return;
    const int beg = offsets[node], end = offsets[node + 1];
    const int c0 = lane * 4;
    const int half = lane >> 5;
    const int hl = lane & 31;

    // ---- phase 1: neighbor mean of h2 (fp16 rows), 2 rows per wave-instr ----
    float acc8[8] = {0.f, 0.f, 0.f, 0.f, 0.f, 0.f, 0.f, 0.f};
    for (int b0 = beg; b0 < end; b0 += 64) {
        const int idx = b0 + lane;
        const int sl = (idx < end) ? ssrc[idx] : 0;
        const int m = min(64, end - b0);
#pragma unroll 8
        for (int kp = 0; kp < m; kp += 2) {
            const int k = kp + half;
            const int s = __shfl(sl, k);
            float4 raw = make_float4(0.f, 0.f, 0.f, 0.f);
            if (k < m) raw = *(const float4*)&h2h[(size_t)s * 256 + hl * 8];
            const float2 f0 = __half22float2(*(const __half2*)&raw.x);
            const float2 f1 = __half22float2(*(const __half2*)&raw.y);
            const float2 f2 = __half22float2(*(const __half2*)&raw.z);
            const float2 f3 = __half22float2(*(const __half2*)&raw.w);
            acc8[0] += f0.x; acc8[1] += f0.y; acc8[2] += f1.x; acc8[3] += f1.y;
            acc8[4] += f2.x; acc8[5] += f2.y; acc8[6] += f3.x; acc8[7] += f3.y;
        }
    }
#pragma unroll
    for (int j = 0; j < 8; ++j) acc8[j] += __shfl(acc8[j], hl + 32);

    const float inv = 1.f / fmaxf((float)(end - beg), 1.f);
    if (half == 0) {
        float4 b0v = make_float4(acc8[0] * inv, acc8[1] * inv, acc8[2] * inv, acc8[3] * inv);
        float4 b1v = make_float4(acc8[4] * inv, acc8[5] * inv, acc8[6] * inv, acc8[7] * inv);
        *(float4*)&xc[(size_t)node * 512 + 256 + hl * 8] = b0v;
        *(float4*)&xc[(size_t)node * 512 + 256 + hl * 8 + 4] = b1v;
        *(float4*)&lds_f[w][256 + hl * 8] = b0v;
        *(float4*)&lds_f[w][256 + hl * 8 + 4] = b1v;
        __half2 q0 = __floats2half2_rn(b0v.x, b0v.y), q1 = __floats2half2_rn(b0v.z, b0v.w);
        __half2 q2 = __floats2half2_rn(b1v.x, b1v.y), q3 = __floats2half2_rn(b1v.z, b1v.w);
        float4 pk;
        *(__half2*)&pk.x = q0; *(__half2*)&pk.y = q1;
        *(__half2*)&pk.z = q2; *(__half2*)&pk.w = q3;
        *(float4*)&lds_h[w][256 + hl * 8] = pk;
    }
    const float4 a = *(const float4*)&xc[(size_t)node * 512 + c0];
    *(float4*)&lds_f[w][c0] = a;
    {
        __half2 a01 = __floats2half2_rn(a.x, a.y), a23 = __floats2half2_rn(a.z, a.w);
        float2 pa;
        *(__half2*)&pa.x = a01; *(__half2*)&pa.y = a23;
        *(float2*)&lds_h[w][c0] = pa;
    }
    // wave-synchronous: same-wave DS ordering + compiler lgkmcnt waits suffice

    const int r = lane & 15;
    const int quad = lane >> 4;

    // ---- phase 2: scores (fp32), 4 classes concurrently, 16-lane reduce ----
    float av[32];
#pragma unroll
    for (int i = 0; i < 8; ++i) {
        const int jj = (i + r) & 7;
        *(float4*)&av[i * 4] = *(const float4*)&lds_f[w][r * 32 + jj * 4];
    }

    float s0, s1;
#pragma unroll
    for (int t = 0; t < 2; ++t) {
        const int c = t * 4 + quad;
        const float* wp = &Wp[c * 512 + r * 32];
        float p = 0.f;
#pragma unroll
        for (int i = 0; i < 8; ++i) {
            const int jj = (i + r) & 7;
            const float4 wv = *(const float4*)&wp[jj * 4];
            p = fmaf(av[i * 4 + 0], wv.x, p);
            p = fmaf(av[i * 4 + 1], wv.y, p);
            p = fmaf(av[i * 4 + 2], wv.z, p);
            p = fmaf(av[i * 4 + 3], wv.w, p);
        }
        p += __shfl_xor(p, 1); p += __shfl_xor(p, 2);
        p += __shfl_xor(p, 4); p += __shfl_xor(p, 8);
        if (t == 0) s0 = p; else s1 = p;
    }
    float best = -3.0e38f;
    int bidx = 0;
#pragma unroll
    for (int c = 0; c < 8; ++c) {
        const float v = __shfl((c < 4) ? s0 : s1, (c & 3) * 16);
        if (v > best) { best = v; bidx = c; }
    }

    // ---- phase 3: expert dots (fp16 x fp16, fp32 accum via fdot2) ----
    float4 ah[4];
#pragma unroll
    for (int i = 0; i < 4; ++i) {
        const int jj = (i + r) & 3;
        ah[i] = *(const float4*)&lds_h[w][r * 32 + jj * 8];
    }

    const __half* web = We_h + (size_t)bidx * 40 * 512;
#pragma unroll
    for (int t = 0; t < 10; ++t) {
        const int c = t * 4 + quad;
        const __half* wr_ = web + c * 512 + r * 32;
        float p = 0.f;
#pragma unroll
        for (int i = 0; i < 4; ++i) {
            const int jj = (i + r) & 3;
            const float4 wv = *(const float4*)&wr_[jj * 8];
            p = dot2acc(ah[i].x, wv.x, p);
            p = dot2acc(ah[i].y, wv.y, p);
            p = dot2acc(ah[i].z, wv.z, p);
            p = dot2acc(ah[i].w, wv.w, p);
        }
        p += __shfl_xor(p, 1); p += __shfl_xor(p, 2);
        p += __shfl_xor(p, 4); p += __shfl_xor(p, 8);
        if (r == 0) out[(size_t)node * 40 + c] = p;
    }
}

extern "C" void kernel_launch(void* const* d_in, const int* in_sizes, int n_in,
                              void* d_out, int out_size, void* d_ws, size_t ws_size,
                              hipStream_t stream) {
    const float* x  = (const float*)d_in[0];
    const int*  edge = (const int*)d_in[1];
    const float* W1 = (const float*)d_in[2];
    const float* b1 = (const float*)d_in[3];
    const float* W2 = (const float*)d_in[4];
    const float* b2 = (const float*)d_in[5];
    const float* Wp = (const float*)d_in[6];
    const float* We = (const float*)d_in[7];

    const int n = in_sizes[0] / 512;   // 50000
    const int e = in_sizes[1] / 2;     // 1600000
    const int half = n / 2;            // 25000
    const int* src = edge;
    const int* dst = edge + e;

    // ---- workspace layout (peak ~164 MB; aliasing documented) ----
    char* ws = (char*)d_ws;
    // regionA (51.2MB): A1h/A2h [half,512] bf16 pair; later t16 [n,256] fp16
    ushort* A1h = (ushort*)ws;
    ushort* A2h = (ushort*)(ws + (size_t)half * 512 * 2);
    __half* t16 = (__half*)ws;                             // aliases A after GEMM1 done
    char* p = ws + (size_t)n * 512 * 2;
    // regionB (51.2MB): h1 fp16 [n,512]; later h2h [n,256] fp16
    __half* h1 = (__half*)p;
    __half* h2h = (__half*)p;                              // aliases h1 after GEMM2 done
    p += (size_t)n * 512 * 2;
    // regionX (51.2MB): x16 fp16 [n,512]
    __half* x16 = (__half*)p; p += (size_t)n * 512 * 2;
    ushort* W1hT = (ushort*)p; p += 512 * 512 * 2;
    ushort* W1lT = (ushort*)p; p += 512 * 512 * 2;
    __half* W2hT = (__half*)p; p += 256 * 512 * 2;
    __half* W2lT = (__half*)p; p += 256 * 512 * 2;
    __half* We_h = (__half*)p; p += 8 * 40 * 512 * 2;
    auto align16 = [](size_t v) { return (v + 15) & ~(size_t)15; };
    float* dinv = (float*)p;    p += align16((size_t)n * 4);
    int* counts = (int*)p;      p += align16((size_t)n * 4);
    int* offsets = (int*)p;     p += align16((size_t)(n + 1) * 4);
    int* cursor = (int*)p;      p += align16((size_t)n * 4);
    int* ssrc = (int*)p;        // [e]

    float* out = (float*)d_out;                 // [n,40]
    float* xc = (float*)d_out + (size_t)n * 40; // [n,512]

    // ---- CSR build ----
    hipMemsetAsync(counts, 0, (size_t)n * 4, stream);
    hist_kernel<<<(e + 255) / 256, 256, 0, stream>>>(dst, counts, e);
    scan_kernel<<<1, 1024, 0, stream>>>(counts, offsets, cursor, dinv, n, e);
    scatter_kernel<<<(e + 255) / 256, 256, 0, stream>>>(src, dst, cursor, ssrc, e);

    // ---- conversions / weight prep ----
    const int total8 = n * 512 / 8;
    xconv_kernel<<<(total8 + 255) / 256, 256, 0, stream>>>(x, x16, total8);
    wsplit_kernel<<<(512 * 512 + 255) / 256, 256, 0, stream>>>(W1, W1hT, W1lT, 512, 9, 511);
    wsplit16_kernel<<<(512 * 256 + 255) / 256, 256, 0, stream>>>(W2, W2hT, W2lT, 512, 8, 255);
    weconv_kernel<<<(8 * 40 * 512 + 255) / 256, 256, 0, stream>>>(We, We_h, 8 * 40 * 512);

    // ---- layer 1 (two M-halves so A-pair fits aliased workspace) ----
    const int waves_half = (half * 64 + 255) / 256;
    for (int h = 0; h < 2; ++h) {
        agg512_kernel<<<waves_half, 256, 0, stream>>>(x16, ssrc, offsets, dinv,
                                                      A1h, A2h, h * half, half);
        dim3 g1(512 / 128, (half + 127) / 128);
        gemm1_kernel<<<g1, 256, 0, stream>>>(
            A1h, A2h, W1hT, W1lT, b1,
            h1 + (size_t)h * half * 512, half, 512, 512);
    }

    // ---- layer 2 GEMM: t16 = fp16(h1 @ W2), f16 2-term MFMA ----
    dim3 g2(256 / 128, (n + 127) / 128);
    gemm2_kernel<<<g2, 256, 0, stream>>>(h1, W2hT, W2lT, t16, n);

    // ---- layer 2 aggregation (fp16 gather) -> xc[:,0:256] + fp16 copy ----
    const int waves_grid = (n * 64 + 255) / 256;
    agg256_kernel<<<waves_grid, 256, 0, stream>>>(t16, ssrc, offsets, dinv, b2, xc, h2h, n);

    // ---- fused neighbor-mean + MoE head ----
    mean_expert_kernel<<<waves_grid, 256, 0, stream>>>(ssrc, offsets, Wp, We_h, h2h, xc, out, n);
}